// Round 1
// 584.886 us; speedup vs baseline: 1.1886x; 1.1886x over previous
//
#include <hip/hip_runtime.h>
#include <hip/hip_fp16.h>

#define HID 64
#define BIN_SHIFT 9
#define BIN_SIZE  512          // 1 << BIN_SHIFT  (dst nodes per bin)
#define SC_TILE   8192         // edges per workgroup in bin_scatter

// R12: scatter_k was top dispatch (110us, WRITE 107MB for a 6.4MB esrc --
// every 4B random write evicted a 64B line across 8 non-coherent L2s).
// Replace one-shot atomic scatter with 2-level counting sort:
//  - bin pass: 512-node bins, per-wg-tile LDS count + 1 global atomic per
//    (wg,bin) segment -> contiguous packed (src<<9|dlow) appends, writes ~9MB.
//  - per-bin csr_count replaces deg_i (coalesced deg writes, no rand atomics).
//  - per-bin csr_scatter: writes confined to bin's ~32KB esrc slice -> one
//    CU's L2 merges lines, writes ~6.4MB.
// packed buffer aliases tmp (build finishes before first gemm). ws ~20.4MB.

__global__ void zero_i(int* __restrict__ p, int n) {
    int i = blockIdx.x * 256 + threadIdx.x, st = gridDim.x * 256;
    for (; i < n; i += st) p[i] = 0;
}

__global__ void dinv_k(const int* __restrict__ deg, float* __restrict__ dinv, int N) {
    int i = blockIdx.x * 256 + threadIdx.x;
    if (i < N) dinv[i] = rsqrtf((float)deg[i] + 1.0f);
}

// ---- bin histogram: LDS hist per wg, one global atomic per (wg,bin) ----
__global__ void bin_count(const int* __restrict__ dst, int* __restrict__ binCount,
                          int E, int nbins) {
    __shared__ int c[1024];
    for (int i = threadIdx.x; i < nbins; i += 256) c[i] = 0;
    __syncthreads();
    int chunk = (E + gridDim.x - 1) / gridDim.x;
    int s0 = blockIdx.x * chunk, s1 = min(E, s0 + chunk);
    for (int e = s0 + threadIdx.x; e < s1; e += 256)
        atomicAdd(&c[dst[e] >> BIN_SHIFT], 1);
    __syncthreads();
    for (int i = threadIdx.x; i < nbins; i += 256)
        if (c[i]) atomicAdd(&binCount[i], c[i]);
}

// ---- exclusive scan over bins (<=1024), init binCursor = binOff ----
__global__ void bin_scan(const int* __restrict__ binCount, int* __restrict__ binOff,
                         int* __restrict__ binCursor, int nb, int E) {
    __shared__ int s[256];
    int t = threadIdx.x, base = t * 4;
    int v0 = 0, v1 = 0, v2 = 0, v3 = 0;
    if (base + 0 < nb) v0 = binCount[base + 0];
    if (base + 1 < nb) v1 = binCount[base + 1];
    if (base + 2 < nb) v2 = binCount[base + 2];
    if (base + 3 < nb) v3 = binCount[base + 3];
    int sum = v0 + v1 + v2 + v3;
    s[t] = sum; __syncthreads();
    for (int off = 1; off < 256; off <<= 1) {
        int x = (t >= off) ? s[t - off] : 0;
        __syncthreads(); s[t] += x; __syncthreads();
    }
    int run = s[t] - sum;
    if (base + 0 < nb) { binOff[base + 0] = run; binCursor[base + 0] = run; } run += v0;
    if (base + 1 < nb) { binOff[base + 1] = run; binCursor[base + 1] = run; } run += v1;
    if (base + 2 < nb) { binOff[base + 2] = run; binCursor[base + 2] = run; } run += v2;
    if (base + 3 < nb) { binOff[base + 3] = run; binCursor[base + 3] = run; } run += v3;
    if (t == 0) binOff[nb] = E;
}

// ---- bin scatter: per-tile LDS count -> segment reservation -> append ----
// writes per (wg,bin) segment are contiguous (~340B) from one CU -> full lines.
__global__ void bin_scatter(const int* __restrict__ src, const int* __restrict__ dst,
                            int* __restrict__ binCursor, unsigned* __restrict__ packed,
                            int E, int nbins) {
    __shared__ int cnt[1024];
    __shared__ int cur[1024];
    int t = threadIdx.x;
    int s0 = blockIdx.x * SC_TILE, s1 = min(E, s0 + SC_TILE);
    for (int i = t; i < nbins; i += 256) cnt[i] = 0;
    __syncthreads();
    for (int e = s0 + t; e < s1; e += 256)
        atomicAdd(&cnt[dst[e] >> BIN_SHIFT], 1);
    __syncthreads();
    for (int b = t; b < nbins; b += 256)
        cur[b] = cnt[b] ? atomicAdd(&binCursor[b], cnt[b]) : 0;
    __syncthreads();
    for (int e = s0 + t; e < s1; e += 256) {       // tile re-read is L2-hot
        int d = dst[e];
        int b = d >> BIN_SHIFT;
        int pos = atomicAdd(&cur[b], 1);
        packed[pos] = ((unsigned)src[e] << BIN_SHIFT) | (unsigned)(d & (BIN_SIZE - 1));
    }
}

// ---- per-bin degree count (replaces deg_i): coalesced deg writes ----
__global__ void csr_count(const unsigned* __restrict__ packed, const int* __restrict__ binOff,
                          int* __restrict__ deg, int N) {
    __shared__ int c[BIN_SIZE];
    int t = threadIdx.x, b = blockIdx.x;
    for (int i = t; i < BIN_SIZE; i += 256) c[i] = 0;
    int j0 = binOff[b], j1 = binOff[b + 1];
    __syncthreads();
    for (int j = j0 + t; j < j1; j += 256)
        atomicAdd(&c[packed[j] & (BIN_SIZE - 1)], 1);
    __syncthreads();
    int base = b << BIN_SHIFT;
    for (int i = t; i < BIN_SIZE; i += 256) {
        int nd = base + i;
        if (nd < N) deg[nd] = c[i];
    }
}

// ---- per-bin CSR scatter: dests confined to bin's ~32KB esrc slice ----
__global__ void csr_scatter(const unsigned* __restrict__ packed, const int* __restrict__ binOff,
                            const int* __restrict__ rp, int* __restrict__ esrc, int N) {
    __shared__ int cur[BIN_SIZE];
    __shared__ int rps[BIN_SIZE];
    int t = threadIdx.x, b = blockIdx.x;
    int base = b << BIN_SHIFT;
    for (int i = t; i < BIN_SIZE; i += 256) {
        cur[i] = 0;
        int nd = base + i;
        rps[i] = (nd < N) ? rp[nd] : 0;
    }
    int j0 = binOff[b], j1 = binOff[b + 1];
    __syncthreads();
    for (int j = j0 + t; j < j1; j += 256) {
        unsigned p = packed[j];
        int dl = p & (BIN_SIZE - 1);
        int pos = rps[dl] + atomicAdd(&cur[dl], 1);
        esrc[pos] = (int)(p >> BIN_SHIFT);
    }
}

// ---- scan stage 1: per-block (1024 elems) exclusive scan + block sums ----
__global__ void scan1(const int* __restrict__ in, int* __restrict__ out,
                      int* __restrict__ bsum, int n) {
    __shared__ int s[256];
    int t = threadIdx.x, base = blockIdx.x * 1024 + t * 4;
    int v0 = 0, v1 = 0, v2 = 0, v3 = 0;
    if (base + 0 < n) v0 = in[base + 0];
    if (base + 1 < n) v1 = in[base + 1];
    if (base + 2 < n) v2 = in[base + 2];
    if (base + 3 < n) v3 = in[base + 3];
    int sum = v0 + v1 + v2 + v3;
    s[t] = sum; __syncthreads();
    for (int off = 1; off < 256; off <<= 1) {
        int x = (t >= off) ? s[t - off] : 0;
        __syncthreads(); s[t] += x; __syncthreads();
    }
    if (t == 255) bsum[blockIdx.x] = s[255];
    int run = s[t] - sum;
    if (base + 0 < n) out[base + 0] = run; run += v0;
    if (base + 1 < n) out[base + 1] = run; run += v1;
    if (base + 2 < n) out[base + 2] = run; run += v2;
    if (base + 3 < n) out[base + 3] = run;
}

__global__ void scan2(int* __restrict__ bsum, int nb) {
    __shared__ int s[256];
    int t = threadIdx.x, base = t * 4;
    int v0 = 0, v1 = 0, v2 = 0, v3 = 0;
    if (base + 0 < nb) v0 = bsum[base + 0];
    if (base + 1 < nb) v1 = bsum[base + 1];
    if (base + 2 < nb) v2 = bsum[base + 2];
    if (base + 3 < nb) v3 = bsum[base + 3];
    int sum = v0 + v1 + v2 + v3;
    s[t] = sum; __syncthreads();
    for (int off = 1; off < 256; off <<= 1) {
        int x = (t >= off) ? s[t - off] : 0;
        __syncthreads(); s[t] += x; __syncthreads();
    }
    int run = s[t] - sum;
    if (base + 0 < nb) bsum[base + 0] = run; run += v0;
    if (base + 1 < nb) bsum[base + 1] = run; run += v1;
    if (base + 2 < nb) bsum[base + 2] = run; run += v2;
    if (base + 3 < nb) bsum[base + 3] = run;
}

__global__ void scan3(int* __restrict__ out, const int* __restrict__ bsum,
                      int n, int N, int E) {
    int i = blockIdx.x * 256 + threadIdx.x;
    if (i < n) out[i] += bsum[i >> 10];
    if (i == 0) out[N] = E;
}

// ---- register-tiled GEMM: tmp'[N,64](fp16) = (H[N,K] @ W[K,64]) * dinv[row] ----
// block = 256 thr, 64x64 tile; thread = 4 rows x 4 cols.
__global__ void gemm_tile(const float* __restrict__ H, const float* __restrict__ W,
                          const float* __restrict__ dinv, __half* __restrict__ out,
                          int N, int K) {
    __shared__ float h_s[64 * 65];   // [row][k], +1 pad
    __shared__ float w_s[64 * 64];   // [k][col]
    int tid  = threadIdx.x;
    int col4 = tid & 15;
    int rq   = (tid >> 4) & 3;
    int wv   = tid >> 6;
    int row0 = wv * 16 + rq * 4;
    int n0   = blockIdx.x * 64;
    float4 acc0 = {0,0,0,0}, acc1 = {0,0,0,0}, acc2 = {0,0,0,0}, acc3 = {0,0,0,0};
    int nchunk = K >> 6;
    for (int kc = 0; kc < nchunk; ++kc) {
        __syncthreads();
        for (int i = tid; i < 64 * 64; i += 256) {
            int r = i >> 6, k = i & 63;
            int nd = n0 + r;
            h_s[r * 65 + k] = (nd < N) ? H[(size_t)nd * K + kc * 64 + k] : 0.0f;
        }
        for (int i = tid; i < 64 * 64; i += 256) {
            int k = i >> 6, c = i & 63;
            w_s[i] = W[(size_t)(kc * 64 + k) * HID + c];
        }
        __syncthreads();
        #pragma unroll 8
        for (int k = 0; k < 64; ++k) {
            float4 w = *(const float4*)&w_s[k * 64 + col4 * 4];
            float h0 = h_s[(row0 + 0) * 65 + k];
            float h1 = h_s[(row0 + 1) * 65 + k];
            float h2 = h_s[(row0 + 2) * 65 + k];
            float h3 = h_s[(row0 + 3) * 65 + k];
            acc0.x = fmaf(h0, w.x, acc0.x); acc0.y = fmaf(h0, w.y, acc0.y);
            acc0.z = fmaf(h0, w.z, acc0.z); acc0.w = fmaf(h0, w.w, acc0.w);
            acc1.x = fmaf(h1, w.x, acc1.x); acc1.y = fmaf(h1, w.y, acc1.y);
            acc1.z = fmaf(h1, w.z, acc1.z); acc1.w = fmaf(h1, w.w, acc1.w);
            acc2.x = fmaf(h2, w.x, acc2.x); acc2.y = fmaf(h2, w.y, acc2.y);
            acc2.z = fmaf(h2, w.z, acc2.z); acc2.w = fmaf(h2, w.w, acc2.w);
            acc3.x = fmaf(h3, w.x, acc3.x); acc3.y = fmaf(h3, w.y, acc3.y);
            acc3.z = fmaf(h3, w.z, acc3.z); acc3.w = fmaf(h3, w.w, acc3.w);
        }
    }
    int nd0 = n0 + row0;
    #pragma unroll
    for (int r = 0; r < 4; ++r) {
        int nd = nd0 + r;
        if (nd < N) {
            float4 a = (r == 0) ? acc0 : (r == 1) ? acc1 : (r == 2) ? acc2 : acc3;
            float dv = dinv[nd];
            __half2* o = (__half2*)&out[(size_t)nd * HID + col4 * 4];
            o[0] = __halves2half2(__float2half_rn(a.x * dv), __float2half_rn(a.y * dv));
            o[1] = __halves2half2(__float2half_rn(a.z * dv), __float2half_rn(a.w * dv));
        }
    }
}

// ---- CSR aggregation, wave per dst node ----
// out[d] = relu?( dinv[d] * (tmp'[d] + sum_j tmp'[esrc_j]) + bias )
__global__ void agg_csr(const __half* __restrict__ tmp, const int* __restrict__ rp,
                        const int* __restrict__ esrc, const float* __restrict__ dinv,
                        const float* __restrict__ bias, float* __restrict__ out,
                        int N, int do_relu) {
    int d = blockIdx.x * 4 + (threadIdx.x >> 6);
    int lane = threadIdx.x & 63;                 // lane == column
    if (d >= N) return;
    float di = dinv[d];
    float accE = __half2float(tmp[(size_t)d * HID + lane]);   // self-loop term
    int j0 = rp[d], j1 = rp[d + 1];
    for (int base = j0; base < j1; base += 64) {
        int cnt = min(64, j1 - base);
        int sp = (lane < cnt) ? esrc[base + lane] : 0;   // coalesced 256B covers 64 edges
        int jj = 0;
        for (; jj + 3 < cnt; jj += 4) {                  // 4 gathers in flight
            int s0 = __shfl(sp, jj + 0);
            int s1 = __shfl(sp, jj + 1);
            int s2 = __shfl(sp, jj + 2);
            int s3 = __shfl(sp, jj + 3);
            float t0 = __half2float(tmp[(size_t)s0 * HID + lane]);
            float t1 = __half2float(tmp[(size_t)s1 * HID + lane]);
            float t2 = __half2float(tmp[(size_t)s2 * HID + lane]);
            float t3 = __half2float(tmp[(size_t)s3 * HID + lane]);
            accE += (t0 + t1) + (t2 + t3);
        }
        for (; jj < cnt; ++jj) {
            int s = __shfl(sp, jj);
            accE += __half2float(tmp[(size_t)s * HID + lane]);
        }
    }
    float v = di * accE;
    if (bias != nullptr) v += bias[lane];
    if (do_relu) v = fmaxf(v, 0.0f);
    out[(size_t)d * HID + lane] = v;
}

extern "C" void kernel_launch(void* const* d_in, const int* in_sizes, int n_in,
                              void* d_out, int out_size, void* d_ws, size_t ws_size,
                              hipStream_t stream) {
    const float* x     = (const float*)d_in[0];   // f32 [N,128]
    const int*   ei    = (const int*)d_in[1];     // int32 [2,E]
    const float* W_in  = (const float*)d_in[2];   // f32 [128,64]
    const float* b_in  = (const float*)d_in[3];   // f32 [64]
    const float* W_h   = (const float*)d_in[4];   // f32 [3,64,64]
    const float* b_h   = (const float*)d_in[5];   // f32 [3,64]
    const float* W_out = (const float*)d_in[6];   // f32 [64,64]

    const int K0 = in_sizes[2] / HID;   // 128
    const int N  = in_sizes[0] / K0;    // 100000
    const int E  = in_sizes[1] / 2;     // 1600000
    const int* srcp = ei;
    const int* dstp = ei + E;

    const int NH = N * HID;
    const size_t Npad = ((size_t)N + 255) & ~(size_t)255;
    const int nbins = (N + BIN_SIZE - 1) >> BIN_SHIFT;   // 196

    float* ACC = (float*)d_out;                   // H buffer / final output f32 [N,64]

    // ws layout (~20.4MB, inside the proven region):
    float*    dinv   = (float*)d_ws;              // Npad f32          0.4 MB
    __half*   tmp    = (__half*)(dinv + Npad);    // NH half          12.8 MB
    unsigned* packed = (unsigned*)tmp;            // E u32 (ALIASES tmp: CSR build
                                                  //  finishes before first gemm)
    int*      degi   = (int*)(tmp + NH);          // Npad              0.4 MB
    int*      rp     = degi + Npad;               // Npad+256          0.4 MB
    int*      bsum   = rp + Npad + 256;           // 1024
    int*      esrc   = bsum + 1024;               // E                 6.4 MB
    int*      binCount  = esrc + E;               // 1024
    int*      binOff    = binCount + 1024;        // 1025
    int*      binCursor = binOff + 1026;          // 1024

    const int tgrid = (N + 63) / 64;
    const int agrid = (N + 3) / 4;
    const int nb    = (N + 1023) / 1024;
    const int sgrid = (E + SC_TILE - 1) / SC_TILE;

    // ---- 2-level counting sort CSR build ----
    zero_i<<<1, 256, 0, stream>>>(binCount, nbins);
    bin_count<<<nbins, 256, 0, stream>>>(dstp, binCount, E, nbins);
    bin_scan<<<1, 256, 0, stream>>>(binCount, binOff, binCursor, nbins, E);
    bin_scatter<<<sgrid, 256, 0, stream>>>(srcp, dstp, binCursor, packed, E, nbins);
    csr_count<<<nbins, 256, 0, stream>>>(packed, binOff, degi, N);
    dinv_k<<<(N + 255) / 256, 256, 0, stream>>>(degi, dinv, N);
    scan1<<<nb, 256, 0, stream>>>(degi, rp, bsum, N);
    scan2<<<1, 256, 0, stream>>>(bsum, nb);
    scan3<<<(N + 255) / 256, 256, 0, stream>>>(rp, bsum, N, N, E);
    csr_scatter<<<nbins, 256, 0, stream>>>(packed, binOff, rp, esrc, N);

    // ---- 5 GCN convs ----
    gemm_tile<<<tgrid, 256, 0, stream>>>(x, W_in, dinv, tmp, N, 128);
    agg_csr<<<agrid, 256, 0, stream>>>(tmp, rp, esrc, dinv, b_in, ACC, N, 0);
    for (int l = 0; l < 3; ++l) {
        gemm_tile<<<tgrid, 256, 0, stream>>>(ACC, W_h + (size_t)l * HID * HID, dinv, tmp, N, 64);
        agg_csr<<<agrid, 256, 0, stream>>>(tmp, rp, esrc, dinv, b_h + (size_t)l * HID, ACC, N, 1);
    }
    gemm_tile<<<tgrid, 256, 0, stream>>>(ACC, W_out, dinv, tmp, N, 64);
    agg_csr<<<agrid, 256, 0, stream>>>(tmp, rp, esrc, dinv, nullptr, ACC, N, 0);
}

// Round 2
// 555.711 us; speedup vs baseline: 1.2510x; 1.0525x over previous
//
#include <hip/hip_runtime.h>
#include <hip/hip_fp16.h>

#define HID 64
#define BIN_SHIFT 9
#define BIN_SIZE  512          // 1 << BIN_SHIFT  (dst nodes per bin)
#define SC_TILE   8192         // edges per workgroup in bin_scatter

// R13: gemm_tile was top (5 x 65us, VALU 33%, HBM 7.5%, Occ 31% -> latency
// bound, 6x off both rooflines). Rebuilt:
//  - 128x64 tile, 8 rows x 4 cols per thread (32 FMA/k vs 16).
//  - H staged TRANSPOSED h_s[k][row], row-stride 132 (132%32=4 -> reads from
//    the wave's 4 row-groups hit banks {0,8,16,24}, conflict-free; 132*4B is
//    16B-divisible so float4 reads stay aligned).
//  - inner loop per k: 3x ds_read_b128 (1 w + 2 h) feeding 32 FMAs -> VALU
//    bound (~64cy/k/CU), LDS pipe at ~20%.
//  - all global staging float4 (was scalar dword).
//  - LDS 49KB -> 3 blocks/CU via __launch_bounds__(256,3).
// CSR build (R12 counting sort) and agg_csr unchanged.

__global__ void zero_i(int* __restrict__ p, int n) {
    int i = blockIdx.x * 256 + threadIdx.x, st = gridDim.x * 256;
    for (; i < n; i += st) p[i] = 0;
}

__global__ void dinv_k(const int* __restrict__ deg, float* __restrict__ dinv, int N) {
    int i = blockIdx.x * 256 + threadIdx.x;
    if (i < N) dinv[i] = rsqrtf((float)deg[i] + 1.0f);
}

// ---- bin histogram: LDS hist per wg, one global atomic per (wg,bin) ----
__global__ void bin_count(const int* __restrict__ dst, int* __restrict__ binCount,
                          int E, int nbins) {
    __shared__ int c[1024];
    for (int i = threadIdx.x; i < nbins; i += 256) c[i] = 0;
    __syncthreads();
    int chunk = (E + gridDim.x - 1) / gridDim.x;
    int s0 = blockIdx.x * chunk, s1 = min(E, s0 + chunk);
    for (int e = s0 + threadIdx.x; e < s1; e += 256)
        atomicAdd(&c[dst[e] >> BIN_SHIFT], 1);
    __syncthreads();
    for (int i = threadIdx.x; i < nbins; i += 256)
        if (c[i]) atomicAdd(&binCount[i], c[i]);
}

// ---- exclusive scan over bins (<=1024), init binCursor = binOff ----
__global__ void bin_scan(const int* __restrict__ binCount, int* __restrict__ binOff,
                         int* __restrict__ binCursor, int nb, int E) {
    __shared__ int s[256];
    int t = threadIdx.x, base = t * 4;
    int v0 = 0, v1 = 0, v2 = 0, v3 = 0;
    if (base + 0 < nb) v0 = binCount[base + 0];
    if (base + 1 < nb) v1 = binCount[base + 1];
    if (base + 2 < nb) v2 = binCount[base + 2];
    if (base + 3 < nb) v3 = binCount[base + 3];
    int sum = v0 + v1 + v2 + v3;
    s[t] = sum; __syncthreads();
    for (int off = 1; off < 256; off <<= 1) {
        int x = (t >= off) ? s[t - off] : 0;
        __syncthreads(); s[t] += x; __syncthreads();
    }
    int run = s[t] - sum;
    if (base + 0 < nb) { binOff[base + 0] = run; binCursor[base + 0] = run; } run += v0;
    if (base + 1 < nb) { binOff[base + 1] = run; binCursor[base + 1] = run; } run += v1;
    if (base + 2 < nb) { binOff[base + 2] = run; binCursor[base + 2] = run; } run += v2;
    if (base + 3 < nb) { binOff[base + 3] = run; binCursor[base + 3] = run; } run += v3;
    if (t == 0) binOff[nb] = E;
}

// ---- bin scatter: per-tile LDS count -> segment reservation -> append ----
__global__ void bin_scatter(const int* __restrict__ src, const int* __restrict__ dst,
                            int* __restrict__ binCursor, unsigned* __restrict__ packed,
                            int E, int nbins) {
    __shared__ int cnt[1024];
    __shared__ int cur[1024];
    int t = threadIdx.x;
    int s0 = blockIdx.x * SC_TILE, s1 = min(E, s0 + SC_TILE);
    for (int i = t; i < nbins; i += 256) cnt[i] = 0;
    __syncthreads();
    for (int e = s0 + t; e < s1; e += 256)
        atomicAdd(&cnt[dst[e] >> BIN_SHIFT], 1);
    __syncthreads();
    for (int b = t; b < nbins; b += 256)
        cur[b] = cnt[b] ? atomicAdd(&binCursor[b], cnt[b]) : 0;
    __syncthreads();
    for (int e = s0 + t; e < s1; e += 256) {       // tile re-read is L2-hot
        int d = dst[e];
        int b = d >> BIN_SHIFT;
        int pos = atomicAdd(&cur[b], 1);
        packed[pos] = ((unsigned)src[e] << BIN_SHIFT) | (unsigned)(d & (BIN_SIZE - 1));
    }
}

// ---- per-bin degree count (replaces deg_i): coalesced deg writes ----
__global__ void csr_count(const unsigned* __restrict__ packed, const int* __restrict__ binOff,
                          int* __restrict__ deg, int N) {
    __shared__ int c[BIN_SIZE];
    int t = threadIdx.x, b = blockIdx.x;
    for (int i = t; i < BIN_SIZE; i += 256) c[i] = 0;
    int j0 = binOff[b], j1 = binOff[b + 1];
    __syncthreads();
    for (int j = j0 + t; j < j1; j += 256)
        atomicAdd(&c[packed[j] & (BIN_SIZE - 1)], 1);
    __syncthreads();
    int base = b << BIN_SHIFT;
    for (int i = t; i < BIN_SIZE; i += 256) {
        int nd = base + i;
        if (nd < N) deg[nd] = c[i];
    }
}

// ---- per-bin CSR scatter: dests confined to bin's ~32KB esrc slice ----
__global__ void csr_scatter(const unsigned* __restrict__ packed, const int* __restrict__ binOff,
                            const int* __restrict__ rp, int* __restrict__ esrc, int N) {
    __shared__ int cur[BIN_SIZE];
    __shared__ int rps[BIN_SIZE];
    int t = threadIdx.x, b = blockIdx.x;
    int base = b << BIN_SHIFT;
    for (int i = t; i < BIN_SIZE; i += 256) {
        cur[i] = 0;
        int nd = base + i;
        rps[i] = (nd < N) ? rp[nd] : 0;
    }
    int j0 = binOff[b], j1 = binOff[b + 1];
    __syncthreads();
    for (int j = j0 + t; j < j1; j += 256) {
        unsigned p = packed[j];
        int dl = p & (BIN_SIZE - 1);
        int pos = rps[dl] + atomicAdd(&cur[dl], 1);
        esrc[pos] = (int)(p >> BIN_SHIFT);
    }
}

// ---- scan stage 1: per-block (1024 elems) exclusive scan + block sums ----
__global__ void scan1(const int* __restrict__ in, int* __restrict__ out,
                      int* __restrict__ bsum, int n) {
    __shared__ int s[256];
    int t = threadIdx.x, base = blockIdx.x * 1024 + t * 4;
    int v0 = 0, v1 = 0, v2 = 0, v3 = 0;
    if (base + 0 < n) v0 = in[base + 0];
    if (base + 1 < n) v1 = in[base + 1];
    if (base + 2 < n) v2 = in[base + 2];
    if (base + 3 < n) v3 = in[base + 3];
    int sum = v0 + v1 + v2 + v3;
    s[t] = sum; __syncthreads();
    for (int off = 1; off < 256; off <<= 1) {
        int x = (t >= off) ? s[t - off] : 0;
        __syncthreads(); s[t] += x; __syncthreads();
    }
    if (t == 255) bsum[blockIdx.x] = s[255];
    int run = s[t] - sum;
    if (base + 0 < n) out[base + 0] = run; run += v0;
    if (base + 1 < n) out[base + 1] = run; run += v1;
    if (base + 2 < n) out[base + 2] = run; run += v2;
    if (base + 3 < n) out[base + 3] = run;
}

__global__ void scan2(int* __restrict__ bsum, int nb) {
    __shared__ int s[256];
    int t = threadIdx.x, base = t * 4;
    int v0 = 0, v1 = 0, v2 = 0, v3 = 0;
    if (base + 0 < nb) v0 = bsum[base + 0];
    if (base + 1 < nb) v1 = bsum[base + 1];
    if (base + 2 < nb) v2 = bsum[base + 2];
    if (base + 3 < nb) v3 = bsum[base + 3];
    int sum = v0 + v1 + v2 + v3;
    s[t] = sum; __syncthreads();
    for (int off = 1; off < 256; off <<= 1) {
        int x = (t >= off) ? s[t - off] : 0;
        __syncthreads(); s[t] += x; __syncthreads();
    }
    int run = s[t] - sum;
    if (base + 0 < nb) bsum[base + 0] = run; run += v0;
    if (base + 1 < nb) bsum[base + 1] = run; run += v1;
    if (base + 2 < nb) bsum[base + 2] = run; run += v2;
    if (base + 3 < nb) bsum[base + 3] = run;
}

__global__ void scan3(int* __restrict__ out, const int* __restrict__ bsum,
                      int n, int N, int E) {
    int i = blockIdx.x * 256 + threadIdx.x;
    if (i < n) out[i] += bsum[i >> 10];
    if (i == 0) out[N] = E;
}

// ---- register-tiled GEMM: tmp'[N,64](fp16) = (H[N,K] @ W[K,64]) * dinv[row] ----
// block = 256 thr, 128x64 tile; thread = 8 rows x 4 cols.
// h_s transposed [k][row] stride 132: conflict-free b128 reads, aligned.
#define HSTRIDE 132
__global__ __launch_bounds__(256, 3)
void gemm_tile(const float* __restrict__ H, const float* __restrict__ W,
               const float* __restrict__ dinv, __half* __restrict__ out,
               int N, int K) {
    __shared__ float h_s[64 * HSTRIDE];   // [k][row]  33 KB
    __shared__ float w_s[64 * 64];        // [k][col]  16 KB
    int tid  = threadIdx.x;
    int col4 = tid & 15;          // output col group (4 cols)
    int row0 = (tid >> 4) * 8;    // 8 rows per thread
    int n0   = blockIdx.x * 128;
    float4 acc[8];
    #pragma unroll
    for (int r = 0; r < 8; ++r) acc[r] = make_float4(0.f, 0.f, 0.f, 0.f);

    int nchunk = K >> 6;
    for (int kc = 0; kc < nchunk; ++kc) {
        __syncthreads();
        // stage H tile (128 rows x 64 k) via float4, store transposed
        #pragma unroll
        for (int m = 0; m < 8; ++m) {
            int i  = tid + m * 256;          // 0..2047
            int r  = i >> 4;
            int k0 = (i & 15) * 4;
            int nd = n0 + r;
            float4 v = make_float4(0.f, 0.f, 0.f, 0.f);
            if (nd < N) v = *(const float4*)&H[(size_t)nd * K + kc * 64 + k0];
            h_s[(k0 + 0) * HSTRIDE + r] = v.x;
            h_s[(k0 + 1) * HSTRIDE + r] = v.y;
            h_s[(k0 + 2) * HSTRIDE + r] = v.z;
            h_s[(k0 + 3) * HSTRIDE + r] = v.w;
        }
        // stage W chunk (64 k x 64 cols) via float4
        #pragma unroll
        for (int m = 0; m < 4; ++m) {
            int i = tid + m * 256;           // 0..1023
            *(float4*)&w_s[i * 4] = *(const float4*)&W[(size_t)(kc * 64) * HID + i * 4];
        }
        __syncthreads();
        #pragma unroll 8
        for (int k = 0; k < 64; ++k) {
            float4 w  = *(const float4*)&w_s[k * 64 + col4 * 4];
            float4 hA = *(const float4*)&h_s[k * HSTRIDE + row0];
            float4 hB = *(const float4*)&h_s[k * HSTRIDE + row0 + 4];
            acc[0].x = fmaf(hA.x, w.x, acc[0].x); acc[0].y = fmaf(hA.x, w.y, acc[0].y);
            acc[0].z = fmaf(hA.x, w.z, acc[0].z); acc[0].w = fmaf(hA.x, w.w, acc[0].w);
            acc[1].x = fmaf(hA.y, w.x, acc[1].x); acc[1].y = fmaf(hA.y, w.y, acc[1].y);
            acc[1].z = fmaf(hA.y, w.z, acc[1].z); acc[1].w = fmaf(hA.y, w.w, acc[1].w);
            acc[2].x = fmaf(hA.z, w.x, acc[2].x); acc[2].y = fmaf(hA.z, w.y, acc[2].y);
            acc[2].z = fmaf(hA.z, w.z, acc[2].z); acc[2].w = fmaf(hA.z, w.w, acc[2].w);
            acc[3].x = fmaf(hA.w, w.x, acc[3].x); acc[3].y = fmaf(hA.w, w.y, acc[3].y);
            acc[3].z = fmaf(hA.w, w.z, acc[3].z); acc[3].w = fmaf(hA.w, w.w, acc[3].w);
            acc[4].x = fmaf(hB.x, w.x, acc[4].x); acc[4].y = fmaf(hB.x, w.y, acc[4].y);
            acc[4].z = fmaf(hB.x, w.z, acc[4].z); acc[4].w = fmaf(hB.x, w.w, acc[4].w);
            acc[5].x = fmaf(hB.y, w.x, acc[5].x); acc[5].y = fmaf(hB.y, w.y, acc[5].y);
            acc[5].z = fmaf(hB.y, w.z, acc[5].z); acc[5].w = fmaf(hB.y, w.w, acc[5].w);
            acc[6].x = fmaf(hB.z, w.x, acc[6].x); acc[6].y = fmaf(hB.z, w.y, acc[6].y);
            acc[6].z = fmaf(hB.z, w.z, acc[6].z); acc[6].w = fmaf(hB.z, w.w, acc[6].w);
            acc[7].x = fmaf(hB.w, w.x, acc[7].x); acc[7].y = fmaf(hB.w, w.y, acc[7].y);
            acc[7].z = fmaf(hB.w, w.z, acc[7].z); acc[7].w = fmaf(hB.w, w.w, acc[7].w);
        }
    }
    int nd0 = n0 + row0;
    #pragma unroll
    for (int r = 0; r < 8; ++r) {
        int nd = nd0 + r;
        if (nd < N) {
            float dv = dinv[nd];
            __half2* o = (__half2*)&out[(size_t)nd * HID + col4 * 4];
            o[0] = __halves2half2(__float2half_rn(acc[r].x * dv), __float2half_rn(acc[r].y * dv));
            o[1] = __halves2half2(__float2half_rn(acc[r].z * dv), __float2half_rn(acc[r].w * dv));
        }
    }
}

// ---- CSR aggregation, wave per dst node ----
// out[d] = relu?( dinv[d] * (tmp'[d] + sum_j tmp'[esrc_j]) + bias )
__global__ void agg_csr(const __half* __restrict__ tmp, const int* __restrict__ rp,
                        const int* __restrict__ esrc, const float* __restrict__ dinv,
                        const float* __restrict__ bias, float* __restrict__ out,
                        int N, int do_relu) {
    int d = blockIdx.x * 4 + (threadIdx.x >> 6);
    int lane = threadIdx.x & 63;                 // lane == column
    if (d >= N) return;
    float di = dinv[d];
    float accE = __half2float(tmp[(size_t)d * HID + lane]);   // self-loop term
    int j0 = rp[d], j1 = rp[d + 1];
    for (int base = j0; base < j1; base += 64) {
        int cnt = min(64, j1 - base);
        int sp = (lane < cnt) ? esrc[base + lane] : 0;   // coalesced 256B covers 64 edges
        int jj = 0;
        for (; jj + 3 < cnt; jj += 4) {                  // 4 gathers in flight
            int s0 = __shfl(sp, jj + 0);
            int s1 = __shfl(sp, jj + 1);
            int s2 = __shfl(sp, jj + 2);
            int s3 = __shfl(sp, jj + 3);
            float t0 = __half2float(tmp[(size_t)s0 * HID + lane]);
            float t1 = __half2float(tmp[(size_t)s1 * HID + lane]);
            float t2 = __half2float(tmp[(size_t)s2 * HID + lane]);
            float t3 = __half2float(tmp[(size_t)s3 * HID + lane]);
            accE += (t0 + t1) + (t2 + t3);
        }
        for (; jj < cnt; ++jj) {
            int s = __shfl(sp, jj);
            accE += __half2float(tmp[(size_t)s * HID + lane]);
        }
    }
    float v = di * accE;
    if (bias != nullptr) v += bias[lane];
    if (do_relu) v = fmaxf(v, 0.0f);
    out[(size_t)d * HID + lane] = v;
}

extern "C" void kernel_launch(void* const* d_in, const int* in_sizes, int n_in,
                              void* d_out, int out_size, void* d_ws, size_t ws_size,
                              hipStream_t stream) {
    const float* x     = (const float*)d_in[0];   // f32 [N,128]
    const int*   ei    = (const int*)d_in[1];     // int32 [2,E]
    const float* W_in  = (const float*)d_in[2];   // f32 [128,64]
    const float* b_in  = (const float*)d_in[3];   // f32 [64]
    const float* W_h   = (const float*)d_in[4];   // f32 [3,64,64]
    const float* b_h   = (const float*)d_in[5];   // f32 [3,64]
    const float* W_out = (const float*)d_in[6];   // f32 [64,64]

    const int K0 = in_sizes[2] / HID;   // 128
    const int N  = in_sizes[0] / K0;    // 100000
    const int E  = in_sizes[1] / 2;     // 1600000
    const int* srcp = ei;
    const int* dstp = ei + E;

    const int NH = N * HID;
    const size_t Npad = ((size_t)N + 255) & ~(size_t)255;
    const int nbins = (N + BIN_SIZE - 1) >> BIN_SHIFT;   // 196

    float* ACC = (float*)d_out;                   // H buffer / final output f32 [N,64]

    // ws layout (~20.4MB, inside the proven region):
    float*    dinv   = (float*)d_ws;              // Npad f32          0.4 MB
    __half*   tmp    = (__half*)(dinv + Npad);    // NH half          12.8 MB
    unsigned* packed = (unsigned*)tmp;            // E u32 (ALIASES tmp: CSR build
                                                  //  finishes before first gemm)
    int*      degi   = (int*)(tmp + NH);          // Npad              0.4 MB
    int*      rp     = degi + Npad;               // Npad+256          0.4 MB
    int*      bsum   = rp + Npad + 256;           // 1024
    int*      esrc   = bsum + 1024;               // E                 6.4 MB
    int*      binCount  = esrc + E;               // 1024
    int*      binOff    = binCount + 1024;        // 1025
    int*      binCursor = binOff + 1026;          // 1024

    const int tgrid = (N + 127) / 128;
    const int agrid = (N + 3) / 4;
    const int nb    = (N + 1023) / 1024;
    const int sgrid = (E + SC_TILE - 1) / SC_TILE;

    // ---- 2-level counting sort CSR build ----
    zero_i<<<1, 256, 0, stream>>>(binCount, nbins);
    bin_count<<<nbins, 256, 0, stream>>>(dstp, binCount, E, nbins);
    bin_scan<<<1, 256, 0, stream>>>(binCount, binOff, binCursor, nbins, E);
    bin_scatter<<<sgrid, 256, 0, stream>>>(srcp, dstp, binCursor, packed, E, nbins);
    csr_count<<<nbins, 256, 0, stream>>>(packed, binOff, degi, N);
    dinv_k<<<(N + 255) / 256, 256, 0, stream>>>(degi, dinv, N);
    scan1<<<nb, 256, 0, stream>>>(degi, rp, bsum, N);
    scan2<<<1, 256, 0, stream>>>(bsum, nb);
    scan3<<<(N + 255) / 256, 256, 0, stream>>>(rp, bsum, N, N, E);
    csr_scatter<<<nbins, 256, 0, stream>>>(packed, binOff, rp, esrc, N);

    // ---- 5 GCN convs ----
    gemm_tile<<<tgrid, 256, 0, stream>>>(x, W_in, dinv, tmp, N, 128);
    agg_csr<<<agrid, 256, 0, stream>>>(tmp, rp, esrc, dinv, b_in, ACC, N, 0);
    for (int l = 0; l < 3; ++l) {
        gemm_tile<<<tgrid, 256, 0, stream>>>(ACC, W_h + (size_t)l * HID * HID, dinv, tmp, N, 64);
        agg_csr<<<agrid, 256, 0, stream>>>(tmp, rp, esrc, dinv, b_h + (size_t)l * HID, ACC, N, 1);
    }
    gemm_tile<<<tgrid, 256, 0, stream>>>(ACC, W_out, dinv, tmp, N, 64);
    agg_csr<<<agrid, 256, 0, stream>>>(tmp, rp, esrc, dinv, nullptr, ACC, N, 0);
}

// Round 5
// 525.730 us; speedup vs baseline: 1.3223x; 1.0570x over previous
//
#include <hip/hip_runtime.h>
#include <hip/hip_fp16.h>

#define HID 64
#define BIN_SHIFT 9
#define BIN_SIZE  512          // 1 << BIN_SHIFT  (dst nodes per bin)
#define SC_TILE   8192         // edges per workgroup in bin_scatter

// R16: R15 failed correctness (absmax 2.09e-2): remainder-loop __shfl was
// INSIDE the divergent `if (e < cnt)` -> ds_bpermute sources only ACTIVE
// lanes; tail edges (deg%16 in 1..8, the common case at avg deg 16) read
// lane values as 0 -> gathered tmp[node 0] instead of the real neighbor.
// Fix: hoist shfl out of the branch (all lanes execute, source lane always
// active via min(e, cnt-1) clamp); only the load/accum stays predicated.
// R14 design otherwise unchanged:
//  - 8 edges per gather instr: lane group g=lane&7 owns cols 8g..8g+7,
//    sub=lane>>3 picks edge; uint4 (16B) per lane -> 1KB/instr, 2-deep.
//  - butterfly __shfl_xor(8/16/32) folds the 8 sub-replicas.
//  - persistent waves: grid=2048.
// gemm_tile (R13 128x64) and CSR build (R12 counting sort) unchanged.

__global__ void zero_i(int* __restrict__ p, int n) {
    int i = blockIdx.x * 256 + threadIdx.x, st = gridDim.x * 256;
    for (; i < n; i += st) p[i] = 0;
}

__global__ void dinv_k(const int* __restrict__ deg, float* __restrict__ dinv, int N) {
    int i = blockIdx.x * 256 + threadIdx.x;
    if (i < N) dinv[i] = rsqrtf((float)deg[i] + 1.0f);
}

// ---- bin histogram: LDS hist per wg, one global atomic per (wg,bin) ----
__global__ void bin_count(const int* __restrict__ dst, int* __restrict__ binCount,
                          int E, int nbins) {
    __shared__ int c[1024];
    for (int i = threadIdx.x; i < nbins; i += 256) c[i] = 0;
    __syncthreads();
    int chunk = (E + gridDim.x - 1) / gridDim.x;
    int s0 = blockIdx.x * chunk, s1 = min(E, s0 + chunk);
    for (int e = s0 + threadIdx.x; e < s1; e += 256)
        atomicAdd(&c[dst[e] >> BIN_SHIFT], 1);
    __syncthreads();
    for (int i = threadIdx.x; i < nbins; i += 256)
        if (c[i]) atomicAdd(&binCount[i], c[i]);
}

// ---- exclusive scan over bins (<=1024), init binCursor = binOff ----
__global__ void bin_scan(const int* __restrict__ binCount, int* __restrict__ binOff,
                         int* __restrict__ binCursor, int nb, int E) {
    __shared__ int s[256];
    int t = threadIdx.x, base = t * 4;
    int v0 = 0, v1 = 0, v2 = 0, v3 = 0;
    if (base + 0 < nb) v0 = binCount[base + 0];
    if (base + 1 < nb) v1 = binCount[base + 1];
    if (base + 2 < nb) v2 = binCount[base + 2];
    if (base + 3 < nb) v3 = binCount[base + 3];
    int sum = v0 + v1 + v2 + v3;
    s[t] = sum; __syncthreads();
    for (int off = 1; off < 256; off <<= 1) {
        int x = (t >= off) ? s[t - off] : 0;
        __syncthreads(); s[t] += x; __syncthreads();
    }
    int run = s[t] - sum;
    if (base + 0 < nb) { binOff[base + 0] = run; binCursor[base + 0] = run; } run += v0;
    if (base + 1 < nb) { binOff[base + 1] = run; binCursor[base + 1] = run; } run += v1;
    if (base + 2 < nb) { binOff[base + 2] = run; binCursor[base + 2] = run; } run += v2;
    if (base + 3 < nb) { binOff[base + 3] = run; binCursor[base + 3] = run; } run += v3;
    if (t == 0) binOff[nb] = E;
}

// ---- bin scatter: per-tile LDS count -> segment reservation -> append ----
__global__ void bin_scatter(const int* __restrict__ src, const int* __restrict__ dst,
                            int* __restrict__ binCursor, unsigned* __restrict__ packed,
                            int E, int nbins) {
    __shared__ int cnt[1024];
    __shared__ int cur[1024];
    int t = threadIdx.x;
    int s0 = blockIdx.x * SC_TILE, s1 = min(E, s0 + SC_TILE);
    for (int i = t; i < nbins; i += 256) cnt[i] = 0;
    __syncthreads();
    for (int e = s0 + t; e < s1; e += 256)
        atomicAdd(&cnt[dst[e] >> BIN_SHIFT], 1);
    __syncthreads();
    for (int b = t; b < nbins; b += 256)
        cur[b] = cnt[b] ? atomicAdd(&binCursor[b], cnt[b]) : 0;
    __syncthreads();
    for (int e = s0 + t; e < s1; e += 256) {       // tile re-read is L2-hot
        int d = dst[e];
        int b = d >> BIN_SHIFT;
        int pos = atomicAdd(&cur[b], 1);
        packed[pos] = ((unsigned)src[e] << BIN_SHIFT) | (unsigned)(d & (BIN_SIZE - 1));
    }
}

// ---- per-bin degree count (replaces deg_i): coalesced deg writes ----
__global__ void csr_count(const unsigned* __restrict__ packed, const int* __restrict__ binOff,
                          int* __restrict__ deg, int N) {
    __shared__ int c[BIN_SIZE];
    int t = threadIdx.x, b = blockIdx.x;
    for (int i = t; i < BIN_SIZE; i += 256) c[i] = 0;
    int j0 = binOff[b], j1 = binOff[b + 1];
    __syncthreads();
    for (int j = j0 + t; j < j1; j += 256)
        atomicAdd(&c[packed[j] & (BIN_SIZE - 1)], 1);
    __syncthreads();
    int base = b << BIN_SHIFT;
    for (int i = t; i < BIN_SIZE; i += 256) {
        int nd = base + i;
        if (nd < N) deg[nd] = c[i];
    }
}

// ---- per-bin CSR scatter: dests confined to bin's ~32KB esrc slice ----
__global__ void csr_scatter(const unsigned* __restrict__ packed, const int* __restrict__ binOff,
                            const int* __restrict__ rp, int* __restrict__ esrc, int N) {
    __shared__ int cur[BIN_SIZE];
    __shared__ int rps[BIN_SIZE];
    int t = threadIdx.x, b = blockIdx.x;
    int base = b << BIN_SHIFT;
    for (int i = t; i < BIN_SIZE; i += 256) {
        cur[i] = 0;
        int nd = base + i;
        rps[i] = (nd < N) ? rp[nd] : 0;
    }
    int j0 = binOff[b], j1 = binOff[b + 1];
    __syncthreads();
    for (int j = j0 + t; j < j1; j += 256) {
        unsigned p = packed[j];
        int dl = p & (BIN_SIZE - 1);
        int pos = rps[dl] + atomicAdd(&cur[dl], 1);
        esrc[pos] = (int)(p >> BIN_SHIFT);
    }
}

// ---- scan stage 1: per-block (1024 elems) exclusive scan + block sums ----
__global__ void scan1(const int* __restrict__ in, int* __restrict__ out,
                      int* __restrict__ bsum, int n) {
    __shared__ int s[256];
    int t = threadIdx.x, base = blockIdx.x * 1024 + t * 4;
    int v0 = 0, v1 = 0, v2 = 0, v3 = 0;
    if (base + 0 < n) v0 = in[base + 0];
    if (base + 1 < n) v1 = in[base + 1];
    if (base + 2 < n) v2 = in[base + 2];
    if (base + 3 < n) v3 = in[base + 3];
    int sum = v0 + v1 + v2 + v3;
    s[t] = sum; __syncthreads();
    for (int off = 1; off < 256; off <<= 1) {
        int x = (t >= off) ? s[t - off] : 0;
        __syncthreads(); s[t] += x; __syncthreads();
    }
    if (t == 255) bsum[blockIdx.x] = s[255];
    int run = s[t] - sum;
    if (base + 0 < n) out[base + 0] = run; run += v0;
    if (base + 1 < n) out[base + 1] = run; run += v1;
    if (base + 2 < n) out[base + 2] = run; run += v2;
    if (base + 3 < n) out[base + 3] = run;
}

__global__ void scan2(int* __restrict__ bsum, int nb) {
    __shared__ int s[256];
    int t = threadIdx.x, base = t * 4;
    int v0 = 0, v1 = 0, v2 = 0, v3 = 0;
    if (base + 0 < nb) v0 = bsum[base + 0];
    if (base + 1 < nb) v1 = bsum[base + 1];
    if (base + 2 < nb) v2 = bsum[base + 2];
    if (base + 3 < nb) v3 = bsum[base + 3];
    int sum = v0 + v1 + v2 + v3;
    s[t] = sum; __syncthreads();
    for (int off = 1; off < 256; off <<= 1) {
        int x = (t >= off) ? s[t - off] : 0;
        __syncthreads(); s[t] += x; __syncthreads();
    }
    int run = s[t] - sum;
    if (base + 0 < nb) bsum[base + 0] = run; run += v0;
    if (base + 1 < nb) bsum[base + 1] = run; run += v1;
    if (base + 2 < nb) bsum[base + 2] = run; run += v2;
    if (base + 3 < nb) bsum[base + 3] = run;
}

__global__ void scan3(int* __restrict__ out, const int* __restrict__ bsum,
                      int n, int N, int E) {
    int i = blockIdx.x * 256 + threadIdx.x;
    if (i < n) out[i] += bsum[i >> 10];
    if (i == 0) out[N] = E;
}

// ---- register-tiled GEMM: tmp'[N,64](fp16) = (H[N,K] @ W[K,64]) * dinv[row] ----
// block = 256 thr, 128x64 tile; thread = 8 rows x 4 cols.
// h_s transposed [k][row] stride 132: conflict-free b128 reads, aligned.
#define HSTRIDE 132
__global__ __launch_bounds__(256, 3)
void gemm_tile(const float* __restrict__ H, const float* __restrict__ W,
               const float* __restrict__ dinv, __half* __restrict__ out,
               int N, int K) {
    __shared__ float h_s[64 * HSTRIDE];   // [k][row]  33 KB
    __shared__ float w_s[64 * 64];        // [k][col]  16 KB
    int tid  = threadIdx.x;
    int col4 = tid & 15;          // output col group (4 cols)
    int row0 = (tid >> 4) * 8;    // 8 rows per thread
    int n0   = blockIdx.x * 128;
    float4 acc[8];
    #pragma unroll
    for (int r = 0; r < 8; ++r) acc[r] = make_float4(0.f, 0.f, 0.f, 0.f);

    int nchunk = K >> 6;
    for (int kc = 0; kc < nchunk; ++kc) {
        __syncthreads();
        // stage H tile (128 rows x 64 k) via float4, store transposed
        #pragma unroll
        for (int m = 0; m < 8; ++m) {
            int i  = tid + m * 256;          // 0..2047
            int r  = i >> 4;
            int k0 = (i & 15) * 4;
            int nd = n0 + r;
            float4 v = make_float4(0.f, 0.f, 0.f, 0.f);
            if (nd < N) v = *(const float4*)&H[(size_t)nd * K + kc * 64 + k0];
            h_s[(k0 + 0) * HSTRIDE + r] = v.x;
            h_s[(k0 + 1) * HSTRIDE + r] = v.y;
            h_s[(k0 + 2) * HSTRIDE + r] = v.z;
            h_s[(k0 + 3) * HSTRIDE + r] = v.w;
        }
        // stage W chunk (64 k x 64 cols) via float4
        #pragma unroll
        for (int m = 0; m < 4; ++m) {
            int i = tid + m * 256;           // 0..1023
            *(float4*)&w_s[i * 4] = *(const float4*)&W[(size_t)(kc * 64) * HID + i * 4];
        }
        __syncthreads();
        #pragma unroll 8
        for (int k = 0; k < 64; ++k) {
            float4 w  = *(const float4*)&w_s[k * 64 + col4 * 4];
            float4 hA = *(const float4*)&h_s[k * HSTRIDE + row0];
            float4 hB = *(const float4*)&h_s[k * HSTRIDE + row0 + 4];
            acc[0].x = fmaf(hA.x, w.x, acc[0].x); acc[0].y = fmaf(hA.x, w.y, acc[0].y);
            acc[0].z = fmaf(hA.x, w.z, acc[0].z); acc[0].w = fmaf(hA.x, w.w, acc[0].w);
            acc[1].x = fmaf(hA.y, w.x, acc[1].x); acc[1].y = fmaf(hA.y, w.y, acc[1].y);
            acc[1].z = fmaf(hA.y, w.z, acc[1].z); acc[1].w = fmaf(hA.y, w.w, acc[1].w);
            acc[2].x = fmaf(hA.z, w.x, acc[2].x); acc[2].y = fmaf(hA.z, w.y, acc[2].y);
            acc[2].z = fmaf(hA.z, w.z, acc[2].z); acc[2].w = fmaf(hA.z, w.w, acc[2].w);
            acc[3].x = fmaf(hA.w, w.x, acc[3].x); acc[3].y = fmaf(hA.w, w.y, acc[3].y);
            acc[3].z = fmaf(hA.w, w.z, acc[3].z); acc[3].w = fmaf(hA.w, w.w, acc[3].w);
            acc[4].x = fmaf(hB.x, w.x, acc[4].x); acc[4].y = fmaf(hB.x, w.y, acc[4].y);
            acc[4].z = fmaf(hB.x, w.z, acc[4].z); acc[4].w = fmaf(hB.x, w.w, acc[4].w);
            acc[5].x = fmaf(hB.y, w.x, acc[5].x); acc[5].y = fmaf(hB.y, w.y, acc[5].y);
            acc[5].z = fmaf(hB.y, w.z, acc[5].z); acc[5].w = fmaf(hB.y, w.w, acc[5].w);
            acc[6].x = fmaf(hB.z, w.x, acc[6].x); acc[6].y = fmaf(hB.z, w.y, acc[6].y);
            acc[6].z = fmaf(hB.z, w.z, acc[6].z); acc[6].w = fmaf(hB.z, w.w, acc[6].w);
            acc[7].x = fmaf(hB.w, w.x, acc[7].x); acc[7].y = fmaf(hB.w, w.y, acc[7].y);
            acc[7].z = fmaf(hB.w, w.z, acc[7].z); acc[7].w = fmaf(hB.w, w.w, acc[7].w);
        }
    }
    int nd0 = n0 + row0;
    #pragma unroll
    for (int r = 0; r < 8; ++r) {
        int nd = nd0 + r;
        if (nd < N) {
            float dv = dinv[nd];
            __half2* o = (__half2*)&out[(size_t)nd * HID + col4 * 4];
            o[0] = __halves2half2(__float2half_rn(acc[r].x * dv), __float2half_rn(acc[r].y * dv));
            o[1] = __halves2half2(__float2half_rn(acc[r].z * dv), __float2half_rn(acc[r].w * dv));
        }
    }
}

// ---- CSR aggregation: 8 edges per gather instr, butterfly combine ----
// lane group g=lane&7 owns cols 8g..8g+7; sub=lane>>3 picks the edge.
// ALL cross-lane shuffles execute with full exec mask (never inside a
// divergent branch -- ds_bpermute sources only ACTIVE lanes on CDNA).
// out[d] = relu?( dinv[d] * (tmp'[d] + sum_j tmp'[esrc_j]) + bias )
__global__ void agg_csr(const __half* __restrict__ tmp, const int* __restrict__ rp,
                        const int* __restrict__ esrc, const float* __restrict__ dinv,
                        const float* __restrict__ bias, float* __restrict__ out,
                        int N, int do_relu) {
    int wave = threadIdx.x >> 6;
    int lane = threadIdx.x & 63;
    int g    = lane & 7;       // col group
    int sub  = lane >> 3;      // edge slot 0..7
    for (int d = blockIdx.x * 4 + wave; d < N; d += gridDim.x * 4) {
        float acc[8];
        #pragma unroll
        for (int i = 0; i < 8; ++i) acc[i] = 0.0f;
        if (sub == 0) {        // self-loop term, counted once
            uint4 v = ((const uint4*)(tmp + (size_t)d * HID))[g];
            const __half2* h2 = (const __half2*)&v;
            #pragma unroll
            for (int i = 0; i < 4; ++i) {
                float2 f = __half22float2(h2[i]);
                acc[2 * i]     = f.x;
                acc[2 * i + 1] = f.y;
            }
        }
        int j0 = rp[d], j1 = rp[d + 1];
        for (int base = j0; base < j1; base += 64) {
            int cnt = min(64, j1 - base);                  // cnt >= 1
            int sp = (lane < cnt) ? esrc[base + lane] : 0;
            int jj = 0;
            for (; jj + 8 < cnt; jj += 16) {     // 2-deep: 2KB in flight
                int e0 = jj + sub;               // e0 < cnt guaranteed
                int e1 = jj + 8 + sub;
                int s0 = __shfl(sp, e0);         // full exec: sources valid
                int s1 = __shfl(sp, e1 & 63);
                bool v1ok = e1 < cnt;
                uint4 v0 = ((const uint4*)(tmp + (size_t)s0 * HID))[g];
                uint4 v1 = make_uint4(0, 0, 0, 0);
                if (v1ok) v1 = ((const uint4*)(tmp + (size_t)s1 * HID))[g];
                const __half2* h0 = (const __half2*)&v0;
                #pragma unroll
                for (int i = 0; i < 4; ++i) {
                    float2 f = __half22float2(h0[i]);
                    acc[2 * i] += f.x; acc[2 * i + 1] += f.y;
                }
                if (v1ok) {
                    const __half2* h1 = (const __half2*)&v1;
                    #pragma unroll
                    for (int i = 0; i < 4; ++i) {
                        float2 f = __half22float2(h1[i]);
                        acc[2 * i] += f.x; acc[2 * i + 1] += f.y;
                    }
                }
            }
            for (; jj < cnt; jj += 8) {          // tail: shfl hoisted OUT of
                int e = jj + sub;                //  the divergent guard
                int s = __shfl(sp, min(e, cnt - 1));   // all lanes execute;
                if (e < cnt) {                         //  source lane active
                    uint4 v = ((const uint4*)(tmp + (size_t)s * HID))[g];
                    const __half2* h2 = (const __half2*)&v;
                    #pragma unroll
                    for (int i = 0; i < 4; ++i) {
                        float2 f = __half22float2(h2[i]);
                        acc[2 * i] += f.x; acc[2 * i + 1] += f.y;
                    }
                }
            }
        }
        // fold the 8 sub replicas (butterfly over lane bits 3,4,5)
        #pragma unroll
        for (int i = 0; i < 8; ++i) {
            float a = acc[i];
            a += __shfl_xor(a, 8);
            a += __shfl_xor(a, 16);
            a += __shfl_xor(a, 32);
            acc[i] = a;
        }
        if (sub == 0) {        // lanes 0..7 write the 256B row
            float di = dinv[d];
            float4 o0, o1;
            o0.x = di * acc[0]; o0.y = di * acc[1];
            o0.z = di * acc[2]; o0.w = di * acc[3];
            o1.x = di * acc[4]; o1.y = di * acc[5];
            o1.z = di * acc[6]; o1.w = di * acc[7];
            if (bias != nullptr) {
                const float4* bp = (const float4*)&bias[g * 8];
                float4 b0 = bp[0], b1 = bp[1];
                o0.x += b0.x; o0.y += b0.y; o0.z += b0.z; o0.w += b0.w;
                o1.x += b1.x; o1.y += b1.y; o1.z += b1.z; o1.w += b1.w;
            }
            if (do_relu) {
                o0.x = fmaxf(o0.x, 0.f); o0.y = fmaxf(o0.y, 0.f);
                o0.z = fmaxf(o0.z, 0.f); o0.w = fmaxf(o0.w, 0.f);
                o1.x = fmaxf(o1.x, 0.f); o1.y = fmaxf(o1.y, 0.f);
                o1.z = fmaxf(o1.z, 0.f); o1.w = fmaxf(o1.w, 0.f);
            }
            float* orow = &out[(size_t)d * HID + g * 8];
            *(float4*)orow       = o0;
            *(float4*)(orow + 4) = o1;
        }
    }
}

extern "C" void kernel_launch(void* const* d_in, const int* in_sizes, int n_in,
                              void* d_out, int out_size, void* d_ws, size_t ws_size,
                              hipStream_t stream) {
    const float* x     = (const float*)d_in[0];   // f32 [N,128]
    const int*   ei    = (const int*)d_in[1];     // int32 [2,E]
    const float* W_in  = (const float*)d_in[2];   // f32 [128,64]
    const float* b_in  = (const float*)d_in[3];   // f32 [64]
    const float* W_h   = (const float*)d_in[4];   // f32 [3,64,64]
    const float* b_h   = (const float*)d_in[5];   // f32 [3,64]
    const float* W_out = (const float*)d_in[6];   // f32 [64,64]

    const int K0 = in_sizes[2] / HID;   // 128
    const int N  = in_sizes[0] / K0;    // 100000
    const int E  = in_sizes[1] / 2;     // 1600000
    const int* srcp = ei;
    const int* dstp = ei + E;

    const int NH = N * HID;
    const size_t Npad = ((size_t)N + 255) & ~(size_t)255;
    const int nbins = (N + BIN_SIZE - 1) >> BIN_SHIFT;   // 196

    float* ACC = (float*)d_out;                   // H buffer / final output f32 [N,64]

    // ws layout (~20.4MB, inside the proven region):
    float*    dinv   = (float*)d_ws;              // Npad f32          0.4 MB
    __half*   tmp    = (__half*)(dinv + Npad);    // NH half          12.8 MB
    unsigned* packed = (unsigned*)tmp;            // E u32 (ALIASES tmp: CSR build
                                                  //  finishes before first gemm)
    int*      degi   = (int*)(tmp + NH);          // Npad              0.4 MB
    int*      rp     = degi + Npad;               // Npad+256          0.4 MB
    int*      bsum   = rp + Npad + 256;           // 1024
    int*      esrc   = bsum + 1024;               // E                 6.4 MB
    int*      binCount  = esrc + E;               // 1024
    int*      binOff    = binCount + 1024;        // 1025
    int*      binCursor = binOff + 1026;          // 1024

    const int tgrid = (N + 127) / 128;
    const int agrid = 2048;                       // persistent waves
    const int nb    = (N + 1023) / 1024;
    const int sgrid = (E + SC_TILE - 1) / SC_TILE;

    // ---- 2-level counting sort CSR build ----
    zero_i<<<1, 256, 0, stream>>>(binCount, nbins);
    bin_count<<<nbins, 256, 0, stream>>>(dstp, binCount, E, nbins);
    bin_scan<<<1, 256, 0, stream>>>(binCount, binOff, binCursor, nbins, E);
    bin_scatter<<<sgrid, 256, 0, stream>>>(srcp, dstp, binCursor, packed, E, nbins);
    csr_count<<<nbins, 256, 0, stream>>>(packed, binOff, degi, N);
    dinv_k<<<(N + 255) / 256, 256, 0, stream>>>(degi, dinv, N);
    scan1<<<nb, 256, 0, stream>>>(degi, rp, bsum, N);
    scan2<<<1, 256, 0, stream>>>(bsum, nb);
    scan3<<<(N + 255) / 256, 256, 0, stream>>>(rp, bsum, N, N, E);
    csr_scatter<<<nbins, 256, 0, stream>>>(packed, binOff, rp, esrc, N);

    // ---- 5 GCN convs ----
    gemm_tile<<<tgrid, 256, 0, stream>>>(x, W_in, dinv, tmp, N, 128);
    agg_csr<<<agrid, 256, 0, stream>>>(tmp, rp, esrc, dinv, b_in, ACC, N, 0);
    for (int l = 0; l < 3; ++l) {
        gemm_tile<<<tgrid, 256, 0, stream>>>(ACC, W_h + (size_t)l * HID * HID, dinv, tmp, N, 64);
        agg_csr<<<agrid, 256, 0, stream>>>(tmp, rp, esrc, dinv, b_h + (size_t)l * HID, ACC, N, 1);
    }
    gemm_tile<<<tgrid, 256, 0, stream>>>(ACC, W_out, dinv, tmp, N, 64);
    agg_csr<<<agrid, 256, 0, stream>>>(tmp, rp, esrc, dinv, nullptr, ACC, N, 0);
}

// Round 7
// 462.729 us; speedup vs baseline: 1.5023x; 1.1362x over previous
//
#include <hip/hip_runtime.h>
#include <hip/hip_fp16.h>

#define HID 64
#define BIN_SHIFT 9
#define BIN_SIZE  512          // 1 << BIN_SHIFT  (dst nodes per bin)
#define SC_TILE   8192         // edges per workgroup in bin_scatter

// R18 == R17 resubmit (container-level failure, same signature as R3's infra
// flake; audit found no fault/hang path, MFMA layouts re-verified against
// m89/m92 evidence). R17 design:
//  - v_mfma_f32_16x16x32_f16 GEMM, f32 accum; wave = 32 rows x 64 cols
//    (2 row-frags x 4 col-frags); block = 128 rows.
//  - A-frags DIRECT from global (16 full-line segs/wave, each H byte read
//    once; no LDS, no barriers, zero bank conflicts).
//  - B-frags from a 48KB fragment-ordered wfrag table (prep kernel, L2-hot).
//  - layers exchange fp16: agg writes h16 (d_out storage) for layers 1-4,
//    f32 only at the end -> halves agg writes AND gemm fetches.
// Frag layouts (m89-verified C/D; m92-verified contiguous-k A/B):
//  A: row=l&15, k=(l>>4)*8+j ; B: col=l&15, same k ; C: col=l&15,
//  row=(l>>4)*4+reg.
// agg_csr (R16 exec-mask-safe shuffles) and CSR build (R12) unchanged.

typedef _Float16 f16x8 __attribute__((ext_vector_type(8)));
typedef float    f32x4 __attribute__((ext_vector_type(4)));

__global__ void zero_i(int* __restrict__ p, int n) {
    int i = blockIdx.x * 256 + threadIdx.x, st = gridDim.x * 256;
    for (; i < n; i += st) p[i] = 0;
}

__global__ void dinv_k(const int* __restrict__ deg, float* __restrict__ dinv, int N) {
    int i = blockIdx.x * 256 + threadIdx.x;
    if (i < N) dinv[i] = rsqrtf((float)deg[i] + 1.0f);
}

// ---- W fragment prep: wfrag[layer][ks][ct][lane][8] fp16 ----
// seg s: 0..15 = W_in (K=128, 4 ks); 16..39 = W_h[0..2] (2 ks each);
// 40..47 = W_out. Within layer: ls = ks*4+ct. 1KB per seg, 48KB total.
__global__ void wfrag_prep(const float* __restrict__ W_in, const float* __restrict__ W_h,
                           const float* __restrict__ W_out, __half* __restrict__ wfrag) {
    int s = blockIdx.x, l = threadIdx.x;
    const float* W; int base, ls;
    if (s < 16)      { W = W_in;                      base = 0;                ls = s; }
    else if (s < 40) { int t = s - 16; int L = t >> 3;
                       W = W_h + (size_t)L * 64 * 64; base = 1024 + L * 512;   ls = t & 7; }
    else             { W = W_out;                     base = 2560;             ls = s - 40; }
    int ks = ls >> 2, ct = ls & 3;
    int col = ct * 16 + (l & 15);
    int k0  = ks * 32 + (l >> 4) * 8;
    __half v[8];
    #pragma unroll
    for (int j = 0; j < 8; ++j) v[j] = __float2half_rn(W[(size_t)(k0 + j) * HID + col]);
    *(uint4*)&wfrag[(size_t)(base + ls * 64 + l) * 8] = *(uint4*)v;
}

// ---- MFMA GEMM: out[N,64](fp16) = (H[N,K] @ W[K,64]) * dinv[row] ----
template<bool IN32, int NKS>
__global__ __launch_bounds__(256)
void gemm_mfma(const void* __restrict__ Hin, const __half* __restrict__ wfl,
               const float* __restrict__ dinv, __half* __restrict__ out, int N) {
    const int l  = threadIdx.x & 63;
    const int wv = threadIdx.x >> 6;
    const int rA = l & 15;        // A row within frag / C col
    const int gK = l >> 4;        // k-group / C row-group
    const int rb = blockIdx.x * 128 + wv * 32;

    // B fragments (L2-hot table, coalesced b128 per frag)
    f16x8 bf[NKS][4];
    #pragma unroll
    for (int ks = 0; ks < NKS; ++ks)
        #pragma unroll
        for (int ct = 0; ct < 4; ++ct)
            bf[ks][ct] = *(const f16x8*)(wfl + (size_t)((ks * 4 + ct) * 64 + l) * 8);

    // A fragments: direct global, full-line segments
    f16x8 af[NKS][2];
    #pragma unroll
    for (int rt = 0; rt < 2; ++rt) {
        int r = rb + rt * 16 + rA; if (r > N - 1) r = N - 1;
        if (IN32) {
            const float* H = (const float*)Hin;
            const float* p = H + (size_t)r * (NKS * 32) + gK * 8;
            #pragma unroll
            for (int ks = 0; ks < NKS; ++ks) {
                f32x4 a = *(const f32x4*)(p + ks * 32);
                f32x4 b = *(const f32x4*)(p + ks * 32 + 4);
                f16x8 t;
                t[0] = (_Float16)a[0]; t[1] = (_Float16)a[1];
                t[2] = (_Float16)a[2]; t[3] = (_Float16)a[3];
                t[4] = (_Float16)b[0]; t[5] = (_Float16)b[1];
                t[6] = (_Float16)b[2]; t[7] = (_Float16)b[3];
                af[ks][rt] = t;
            }
        } else {
            const __half* H = (const __half*)Hin;
            #pragma unroll
            for (int ks = 0; ks < NKS; ++ks)
                af[ks][rt] = *(const f16x8*)(H + (size_t)r * HID + ks * 32 + gK * 8);
        }
    }

    f32x4 acc[2][4];
    #pragma unroll
    for (int rt = 0; rt < 2; ++rt)
        #pragma unroll
        for (int ct = 0; ct < 4; ++ct)
            acc[rt][ct] = (f32x4){0.f, 0.f, 0.f, 0.f};

    #pragma unroll
    for (int ks = 0; ks < NKS; ++ks)
        #pragma unroll
        for (int rt = 0; rt < 2; ++rt)
            #pragma unroll
            for (int ct = 0; ct < 4; ++ct)
                acc[rt][ct] = __builtin_amdgcn_mfma_f32_16x16x32_f16(
                    af[ks][rt], bf[ks][ct], acc[rt][ct], 0, 0, 0);

    // epilogue: C row = (l>>4)*4 + reg, col = ct*16 + (l&15)
    #pragma unroll
    for (int rt = 0; rt < 2; ++rt) {
        int r0 = rb + rt * 16 + gK * 4;
        float dv[4];
        #pragma unroll
        for (int j = 0; j < 4; ++j) dv[j] = dinv[min(r0 + j, N - 1)];
        #pragma unroll
        for (int ct = 0; ct < 4; ++ct)
            #pragma unroll
            for (int j = 0; j < 4; ++j) {
                int r = r0 + j;
                if (r < N)
                    out[(size_t)r * HID + ct * 16 + rA] =
                        __float2half_rn(acc[rt][ct][j] * dv[j]);
            }
    }
}

// ---- bin histogram: LDS hist per wg, one global atomic per (wg,bin) ----
__global__ void bin_count(const int* __restrict__ dst, int* __restrict__ binCount,
                          int E, int nbins) {
    __shared__ int c[1024];
    for (int i = threadIdx.x; i < nbins; i += 256) c[i] = 0;
    __syncthreads();
    int chunk = (E + gridDim.x - 1) / gridDim.x;
    int s0 = blockIdx.x * chunk, s1 = min(E, s0 + chunk);
    for (int e = s0 + threadIdx.x; e < s1; e += 256)
        atomicAdd(&c[dst[e] >> BIN_SHIFT], 1);
    __syncthreads();
    for (int i = threadIdx.x; i < nbins; i += 256)
        if (c[i]) atomicAdd(&binCount[i], c[i]);
}

// ---- exclusive scan over bins (<=1024), init binCursor = binOff ----
__global__ void bin_scan(const int* __restrict__ binCount, int* __restrict__ binOff,
                         int* __restrict__ binCursor, int nb, int E) {
    __shared__ int s[256];
    int t = threadIdx.x, base = t * 4;
    int v0 = 0, v1 = 0, v2 = 0, v3 = 0;
    if (base + 0 < nb) v0 = binCount[base + 0];
    if (base + 1 < nb) v1 = binCount[base + 1];
    if (base + 2 < nb) v2 = binCount[base + 2];
    if (base + 3 < nb) v3 = binCount[base + 3];
    int sum = v0 + v1 + v2 + v3;
    s[t] = sum; __syncthreads();
    for (int off = 1; off < 256; off <<= 1) {
        int x = (t >= off) ? s[t - off] : 0;
        __syncthreads(); s[t] += x; __syncthreads();
    }
    int run = s[t] - sum;
    if (base + 0 < nb) { binOff[base + 0] = run; binCursor[base + 0] = run; } run += v0;
    if (base + 1 < nb) { binOff[base + 1] = run; binCursor[base + 1] = run; } run += v1;
    if (base + 2 < nb) { binOff[base + 2] = run; binCursor[base + 2] = run; } run += v2;
    if (base + 3 < nb) { binOff[base + 3] = run; binCursor[base + 3] = run; } run += v3;
    if (t == 0) binOff[nb] = E;
}

// ---- bin scatter: per-tile LDS count -> segment reservation -> append ----
__global__ void bin_scatter(const int* __restrict__ src, const int* __restrict__ dst,
                            int* __restrict__ binCursor, unsigned* __restrict__ packed,
                            int E, int nbins) {
    __shared__ int cnt[1024];
    __shared__ int cur[1024];
    int t = threadIdx.x;
    int s0 = blockIdx.x * SC_TILE, s1 = min(E, s0 + SC_TILE);
    for (int i = t; i < nbins; i += 256) cnt[i] = 0;
    __syncthreads();
    for (int e = s0 + t; e < s1; e += 256)
        atomicAdd(&cnt[dst[e] >> BIN_SHIFT], 1);
    __syncthreads();
    for (int b = t; b < nbins; b += 256)
        cur[b] = cnt[b] ? atomicAdd(&binCursor[b], cnt[b]) : 0;
    __syncthreads();
    for (int e = s0 + t; e < s1; e += 256) {       // tile re-read is L2-hot
        int d = dst[e];
        int b = d >> BIN_SHIFT;
        int pos = atomicAdd(&cur[b], 1);
        packed[pos] = ((unsigned)src[e] << BIN_SHIFT) | (unsigned)(d & (BIN_SIZE - 1));
    }
}

// ---- per-bin degree count: coalesced deg writes ----
__global__ void csr_count(const unsigned* __restrict__ packed, const int* __restrict__ binOff,
                          int* __restrict__ deg, int N) {
    __shared__ int c[BIN_SIZE];
    int t = threadIdx.x, b = blockIdx.x;
    for (int i = t; i < BIN_SIZE; i += 256) c[i] = 0;
    int j0 = binOff[b], j1 = binOff[b + 1];
    __syncthreads();
    for (int j = j0 + t; j < j1; j += 256)
        atomicAdd(&c[packed[j] & (BIN_SIZE - 1)], 1);
    __syncthreads();
    int base = b << BIN_SHIFT;
    for (int i = t; i < BIN_SIZE; i += 256) {
        int nd = base + i;
        if (nd < N) deg[nd] = c[i];
    }
}

// ---- per-bin CSR scatter: dests confined to bin's ~32KB esrc slice ----
__global__ void csr_scatter(const unsigned* __restrict__ packed, const int* __restrict__ binOff,
                            const int* __restrict__ rp, int* __restrict__ esrc, int N) {
    __shared__ int cur[BIN_SIZE];
    __shared__ int rps[BIN_SIZE];
    int t = threadIdx.x, b = blockIdx.x;
    int base = b << BIN_SHIFT;
    for (int i = t; i < BIN_SIZE; i += 256) {
        cur[i] = 0;
        int nd = base + i;
        rps[i] = (nd < N) ? rp[nd] : 0;
    }
    int j0 = binOff[b], j1 = binOff[b + 1];
    __syncthreads();
    for (int j = j0 + t; j < j1; j += 256) {
        unsigned p = packed[j];
        int dl = p & (BIN_SIZE - 1);
        int pos = rps[dl] + atomicAdd(&cur[dl], 1);
        esrc[pos] = (int)(p >> BIN_SHIFT);
    }
}

// ---- scan stage 1: per-block (1024 elems) exclusive scan + block sums ----
__global__ void scan1(const int* __restrict__ in, int* __restrict__ out,
                      int* __restrict__ bsum, int n) {
    __shared__ int s[256];
    int t = threadIdx.x, base = blockIdx.x * 1024 + t * 4;
    int v0 = 0, v1 = 0, v2 = 0, v3 = 0;
    if (base + 0 < n) v0 = in[base + 0];
    if (base + 1 < n) v1 = in[base + 1];
    if (base + 2 < n) v2 = in[base + 2];
    if (base + 3 < n) v3 = in[base + 3];
    int sum = v0 + v1 + v2 + v3;
    s[t] = sum; __syncthreads();
    for (int off = 1; off < 256; off <<= 1) {
        int x = (t >= off) ? s[t - off] : 0;
        __syncthreads(); s[t] += x; __syncthreads();
    }
    if (t == 255) bsum[blockIdx.x] = s[255];
    int run = s[t] - sum;
    if (base + 0 < n) out[base + 0] = run; run += v0;
    if (base + 1 < n) out[base + 1] = run; run += v1;
    if (base + 2 < n) out[base + 2] = run; run += v2;
    if (base + 3 < n) out[base + 3] = run;
}

__global__ void scan2(int* __restrict__ bsum, int nb) {
    __shared__ int s[256];
    int t = threadIdx.x, base = t * 4;
    int v0 = 0, v1 = 0, v2 = 0, v3 = 0;
    if (base + 0 < nb) v0 = bsum[base + 0];
    if (base + 1 < nb) v1 = bsum[base + 1];
    if (base + 2 < nb) v2 = bsum[base + 2];
    if (base + 3 < nb) v3 = bsum[base + 3];
    int sum = v0 + v1 + v2 + v3;
    s[t] = sum; __syncthreads();
    for (int off = 1; off < 256; off <<= 1) {
        int x = (t >= off) ? s[t - off] : 0;
        __syncthreads(); s[t] += x; __syncthreads();
    }
    int run = s[t] - sum;
    if (base + 0 < nb) bsum[base + 0] = run; run += v0;
    if (base + 1 < nb) bsum[base + 1] = run; run += v1;
    if (base + 2 < nb) bsum[base + 2] = run; run += v2;
    if (base + 3 < nb) bsum[base + 3] = run;
}

__global__ void scan3(int* __restrict__ out, const int* __restrict__ bsum,
                      int n, int N, int E) {
    int i = blockIdx.x * 256 + threadIdx.x;
    if (i < n) out[i] += bsum[i >> 10];
    if (i == 0) out[N] = E;
}

// ---- CSR aggregation: 8 edges per gather instr, butterfly combine ----
// lane group g=lane&7 owns cols 8g..8g+7; sub=lane>>3 picks the edge.
// ALL cross-lane shuffles execute with full exec mask (R16 lesson).
// out = relu?( dinv[d] * (tmp'[d] + sum_j tmp'[esrc_j]) + bias )
// writes fp16 (houtp) for intermediate layers, f32 (outf) for the last.
__global__ void agg_csr(const __half* __restrict__ tmp, const int* __restrict__ rp,
                        const int* __restrict__ esrc, const float* __restrict__ dinv,
                        const float* __restrict__ bias, float* __restrict__ outf,
                        __half* __restrict__ houtp, int N, int do_relu) {
    int wave = threadIdx.x >> 6;
    int lane = threadIdx.x & 63;
    int g    = lane & 7;       // col group
    int sub  = lane >> 3;      // edge slot 0..7
    for (int d = blockIdx.x * 4 + wave; d < N; d += gridDim.x * 4) {
        float acc[8];
        #pragma unroll
        for (int i = 0; i < 8; ++i) acc[i] = 0.0f;
        if (sub == 0) {        // self-loop term, counted once
            uint4 v = ((const uint4*)(tmp + (size_t)d * HID))[g];
            const __half2* h2 = (const __half2*)&v;
            #pragma unroll
            for (int i = 0; i < 4; ++i) {
                float2 f = __half22float2(h2[i]);
                acc[2 * i]     = f.x;
                acc[2 * i + 1] = f.y;
            }
        }
        int j0 = rp[d], j1 = rp[d + 1];
        for (int base = j0; base < j1; base += 64) {
            int cnt = min(64, j1 - base);                  // cnt >= 1
            int sp = (lane < cnt) ? esrc[base + lane] : 0;
            int jj = 0;
            for (; jj + 8 < cnt; jj += 16) {     // 2-deep: 2KB in flight
                int e0 = jj + sub;               // e0 < cnt guaranteed
                int e1 = jj + 8 + sub;
                int s0 = __shfl(sp, e0);         // full exec: sources valid
                int s1 = __shfl(sp, e1 & 63);
                bool v1ok = e1 < cnt;
                uint4 v0 = ((const uint4*)(tmp + (size_t)s0 * HID))[g];
                uint4 v1 = make_uint4(0, 0, 0, 0);
                if (v1ok) v1 = ((const uint4*)(tmp + (size_t)s1 * HID))[g];
                const __half2* h0 = (const __half2*)&v0;
                #pragma unroll
                for (int i = 0; i < 4; ++i) {
                    float2 f = __half22float2(h0[i]);
                    acc[2 * i] += f.x; acc[2 * i + 1] += f.y;
                }
                if (v1ok) {
                    const __half2* h1 = (const __half2*)&v1;
                    #pragma unroll
                    for (int i = 0; i < 4; ++i) {
                        float2 f = __half22float2(h1[i]);
                        acc[2 * i] += f.x; acc[2 * i + 1] += f.y;
                    }
                }
            }
            for (; jj < cnt; jj += 8) {          // tail: shfl OUTSIDE guard
                int e = jj + sub;
                int s = __shfl(sp, min(e, cnt - 1));
                if (e < cnt) {
                    uint4 v = ((const uint4*)(tmp + (size_t)s * HID))[g];
                    const __half2* h2 = (const __half2*)&v;
                    #pragma unroll
                    for (int i = 0; i < 4; ++i) {
                        float2 f = __half22float2(h2[i]);
                        acc[2 * i] += f.x; acc[2 * i + 1] += f.y;
                    }
                }
            }
        }
        // fold the 8 sub replicas (butterfly over lane bits 3,4,5)
        #pragma unroll
        for (int i = 0; i < 8; ++i) {
            float a = acc[i];
            a += __shfl_xor(a, 8);
            a += __shfl_xor(a, 16);
            a += __shfl_xor(a, 32);
            acc[i] = a;
        }
        if (sub == 0) {        // lanes 0..7 hold the row
            float di = dinv[d];
            float o[8];
            #pragma unroll
            for (int i = 0; i < 8; ++i) o[i] = di * acc[i];
            if (bias != nullptr) {
                #pragma unroll
                for (int i = 0; i < 8; ++i) o[i] += bias[g * 8 + i];
            }
            if (do_relu) {
                #pragma unroll
                for (int i = 0; i < 8; ++i) o[i] = fmaxf(o[i], 0.0f);
            }
            if (houtp != nullptr) {              // fp16 row: 16B per lane
                __half2 ph[4];
                #pragma unroll
                for (int i = 0; i < 4; ++i)
                    ph[i] = __halves2half2(__float2half_rn(o[2 * i]),
                                           __float2half_rn(o[2 * i + 1]));
                *(uint4*)&houtp[(size_t)d * HID + g * 8] = *(uint4*)ph;
            } else {
                float* orow = &outf[(size_t)d * HID + g * 8];
                *(float4*)orow       = make_float4(o[0], o[1], o[2], o[3]);
                *(float4*)(orow + 4) = make_float4(o[4], o[5], o[6], o[7]);
            }
        }
    }
}

extern "C" void kernel_launch(void* const* d_in, const int* in_sizes, int n_in,
                              void* d_out, int out_size, void* d_ws, size_t ws_size,
                              hipStream_t stream) {
    const float* x     = (const float*)d_in[0];   // f32 [N,128]
    const int*   ei    = (const int*)d_in[1];     // int32 [2,E]
    const float* W_in  = (const float*)d_in[2];   // f32 [128,64]
    const float* b_in  = (const float*)d_in[3];   // f32 [64]
    const float* W_h   = (const float*)d_in[4];   // f32 [3,64,64]
    const float* b_h   = (const float*)d_in[5];   // f32 [3,64]
    const float* W_out = (const float*)d_in[6];   // f32 [64,64]

    const int K0 = in_sizes[2] / HID;   // 128
    const int N  = in_sizes[0] / K0;    // 100000
    const int E  = in_sizes[1] / 2;     // 1600000
    const int* srcp = ei;
    const int* dstp = ei + E;

    const int NH = N * HID;
    const size_t Npad = ((size_t)N + 255) & ~(size_t)255;
    const int nbins = (N + BIN_SIZE - 1) >> BIN_SHIFT;   // 196

    float*  ACC = (float*)d_out;                  // final output f32 [N,64]
    __half* h16 = (__half*)d_out;                 // intermediate H fp16 (same storage)

    // ws layout (~20.5MB, inside the proven region):
    float*    dinv   = (float*)d_ws;              // Npad f32          0.4 MB
    __half*   tmp    = (__half*)(dinv + Npad);    // NH half          12.8 MB
    unsigned* packed = (unsigned*)tmp;            // E u32 (ALIASES tmp: CSR build
                                                  //  finishes before first gemm)
    int*      degi   = (int*)(tmp + NH);          // Npad              0.4 MB
    int*      rp     = degi + Npad;               // Npad+256          0.4 MB
    int*      bsum   = rp + Npad + 256;           // 1024
    int*      esrc   = bsum + 1024;               // E                 6.4 MB
    int*      binCount  = esrc + E;               // 1024
    int*      binOff    = binCount + 1024;        // 1025
    int*      binCursor = binOff + 1026;          // 1024
    uintptr_t wf_addr = (uintptr_t)(binCursor + 1024);
    wf_addr = (wf_addr + 15) & ~(uintptr_t)15;
    __half*   wfrag  = (__half*)wf_addr;          // 3072 x 8 fp16    48 KB

    const int tgrid = (N + 127) / 128;
    const int agrid = 2048;                       // persistent waves
    const int nb    = (N + 1023) / 1024;
    const int sgrid = (E + SC_TILE - 1) / SC_TILE;

    // ---- W fragment prep + 2-level counting sort CSR build ----
    wfrag_prep<<<48, 64, 0, stream>>>(W_in, W_h, W_out, wfrag);
    zero_i<<<1, 256, 0, stream>>>(binCount, nbins);
    bin_count<<<nbins, 256, 0, stream>>>(dstp, binCount, E, nbins);
    bin_scan<<<1, 256, 0, stream>>>(binCount, binOff, binCursor, nbins, E);
    bin_scatter<<<sgrid, 256, 0, stream>>>(srcp, dstp, binCursor, packed, E, nbins);
    csr_count<<<nbins, 256, 0, stream>>>(packed, binOff, degi, N);
    dinv_k<<<(N + 255) / 256, 256, 0, stream>>>(degi, dinv, N);
    scan1<<<nb, 256, 0, stream>>>(degi, rp, bsum, N);
    scan2<<<1, 256, 0, stream>>>(bsum, nb);
    scan3<<<(N + 255) / 256, 256, 0, stream>>>(rp, bsum, N, N, E);
    csr_scatter<<<nbins, 256, 0, stream>>>(packed, binOff, rp, esrc, N);

    // ---- 5 GCN convs (MFMA GEMMs; fp16 inter-layer H) ----
    gemm_mfma<true, 4><<<tgrid, 256, 0, stream>>>(x, wfrag, dinv, tmp, N);
    agg_csr<<<agrid, 256, 0, stream>>>(tmp, rp, esrc, dinv, b_in, nullptr, h16, N, 0);
    for (int l = 0; l < 3; ++l) {
        gemm_mfma<false, 2><<<tgrid, 256, 0, stream>>>(
            h16, wfrag + (size_t)(1024 + l * 512) * 8, dinv, tmp, N);
        agg_csr<<<agrid, 256, 0, stream>>>(tmp, rp, esrc, dinv, b_h + (size_t)l * HID,
                                           nullptr, h16, N, 1);
    }
    gemm_mfma<false, 2><<<tgrid, 256, 0, stream>>>(
        h16, wfrag + (size_t)2560 * 8, dinv, tmp, N);
    agg_csr<<<agrid, 256, 0, stream>>>(tmp, rp, esrc, dinv, nullptr, ACC, nullptr, N, 0);
}

// Round 8
// 442.217 us; speedup vs baseline: 1.5720x; 1.0464x over previous
//
#include <hip/hip_runtime.h>
#include <hip/hip_fp16.h>

#define HID 64
#define BIN_SHIFT 9
#define BIN_SIZE  512          // 1 << BIN_SHIFT  (dst nodes per bin)
#define SC_TILE   8192         // edges per workgroup in bin_scatter

// R19: agg_csr top again (5 x 49us = 53%; VALU 42%, HBM 26%, Occ 70% ->
// latency-bound: per-node serial chain rp->esrc->shfl->gather exposed ~12x
// per wave). Software-pipelined the node loop:
//  - rp[dn] prefetched at iteration top (consumed a full node later),
//  - next node's esrc chunk prefetched right after the gather loop,
//  - wave-uniform loop sections (16-edge 2-deep unguarded / 8-edge unguarded
//    / clamped tail) keep every __shfl at full exec (R16 lesson),
//  - branchless self-loop load.
// f32 accumulation unchanged (bit-compatible). gemm_mfma (R17) and CSR
// build (R12 counting sort) unchanged.

typedef _Float16 f16x8 __attribute__((ext_vector_type(8)));
typedef float    f32x4 __attribute__((ext_vector_type(4)));

__global__ void zero_i(int* __restrict__ p, int n) {
    int i = blockIdx.x * 256 + threadIdx.x, st = gridDim.x * 256;
    for (; i < n; i += st) p[i] = 0;
}

__global__ void dinv_k(const int* __restrict__ deg, float* __restrict__ dinv, int N) {
    int i = blockIdx.x * 256 + threadIdx.x;
    if (i < N) dinv[i] = rsqrtf((float)deg[i] + 1.0f);
}

// ---- W fragment prep: wfrag[layer][ks][ct][lane][8] fp16 ----
__global__ void wfrag_prep(const float* __restrict__ W_in, const float* __restrict__ W_h,
                           const float* __restrict__ W_out, __half* __restrict__ wfrag) {
    int s = blockIdx.x, l = threadIdx.x;
    const float* W; int base, ls;
    if (s < 16)      { W = W_in;                      base = 0;                ls = s; }
    else if (s < 40) { int t = s - 16; int L = t >> 3;
                       W = W_h + (size_t)L * 64 * 64; base = 1024 + L * 512;   ls = t & 7; }
    else             { W = W_out;                     base = 2560;             ls = s - 40; }
    int ks = ls >> 2, ct = ls & 3;
    int col = ct * 16 + (l & 15);
    int k0  = ks * 32 + (l >> 4) * 8;
    __half v[8];
    #pragma unroll
    for (int j = 0; j < 8; ++j) v[j] = __float2half_rn(W[(size_t)(k0 + j) * HID + col]);
    *(uint4*)&wfrag[(size_t)(base + ls * 64 + l) * 8] = *(uint4*)v;
}

// ---- MFMA GEMM: out[N,64](fp16) = (H[N,K] @ W[K,64]) * dinv[row] ----
template<bool IN32, int NKS>
__global__ __launch_bounds__(256)
void gemm_mfma(const void* __restrict__ Hin, const __half* __restrict__ wfl,
               const float* __restrict__ dinv, __half* __restrict__ out, int N) {
    const int l  = threadIdx.x & 63;
    const int wv = threadIdx.x >> 6;
    const int rA = l & 15;        // A row within frag / C col
    const int gK = l >> 4;        // k-group / C row-group
    const int rb = blockIdx.x * 128 + wv * 32;

    f16x8 bf[NKS][4];
    #pragma unroll
    for (int ks = 0; ks < NKS; ++ks)
        #pragma unroll
        for (int ct = 0; ct < 4; ++ct)
            bf[ks][ct] = *(const f16x8*)(wfl + (size_t)((ks * 4 + ct) * 64 + l) * 8);

    f16x8 af[NKS][2];
    #pragma unroll
    for (int rt = 0; rt < 2; ++rt) {
        int r = rb + rt * 16 + rA; if (r > N - 1) r = N - 1;
        if (IN32) {
            const float* H = (const float*)Hin;
            const float* p = H + (size_t)r * (NKS * 32) + gK * 8;
            #pragma unroll
            for (int ks = 0; ks < NKS; ++ks) {
                f32x4 a = *(const f32x4*)(p + ks * 32);
                f32x4 b = *(const f32x4*)(p + ks * 32 + 4);
                f16x8 t;
                t[0] = (_Float16)a[0]; t[1] = (_Float16)a[1];
                t[2] = (_Float16)a[2]; t[3] = (_Float16)a[3];
                t[4] = (_Float16)b[0]; t[5] = (_Float16)b[1];
                t[6] = (_Float16)b[2]; t[7] = (_Float16)b[3];
                af[ks][rt] = t;
            }
        } else {
            const __half* H = (const __half*)Hin;
            #pragma unroll
            for (int ks = 0; ks < NKS; ++ks)
                af[ks][rt] = *(const f16x8*)(H + (size_t)r * HID + ks * 32 + gK * 8);
        }
    }

    f32x4 acc[2][4];
    #pragma unroll
    for (int rt = 0; rt < 2; ++rt)
        #pragma unroll
        for (int ct = 0; ct < 4; ++ct)
            acc[rt][ct] = (f32x4){0.f, 0.f, 0.f, 0.f};

    #pragma unroll
    for (int ks = 0; ks < NKS; ++ks)
        #pragma unroll
        for (int rt = 0; rt < 2; ++rt)
            #pragma unroll
            for (int ct = 0; ct < 4; ++ct)
                acc[rt][ct] = __builtin_amdgcn_mfma_f32_16x16x32_f16(
                    af[ks][rt], bf[ks][ct], acc[rt][ct], 0, 0, 0);

    #pragma unroll
    for (int rt = 0; rt < 2; ++rt) {
        int r0 = rb + rt * 16 + gK * 4;
        float dv[4];
        #pragma unroll
        for (int j = 0; j < 4; ++j) dv[j] = dinv[min(r0 + j, N - 1)];
        #pragma unroll
        for (int ct = 0; ct < 4; ++ct)
            #pragma unroll
            for (int j = 0; j < 4; ++j) {
                int r = r0 + j;
                if (r < N)
                    out[(size_t)r * HID + ct * 16 + rA] =
                        __float2half_rn(acc[rt][ct][j] * dv[j]);
            }
    }
}

// ---- bin histogram: LDS hist per wg, one global atomic per (wg,bin) ----
__global__ void bin_count(const int* __restrict__ dst, int* __restrict__ binCount,
                          int E, int nbins) {
    __shared__ int c[1024];
    for (int i = threadIdx.x; i < nbins; i += 256) c[i] = 0;
    __syncthreads();
    int chunk = (E + gridDim.x - 1) / gridDim.x;
    int s0 = blockIdx.x * chunk, s1 = min(E, s0 + chunk);
    for (int e = s0 + threadIdx.x; e < s1; e += 256)
        atomicAdd(&c[dst[e] >> BIN_SHIFT], 1);
    __syncthreads();
    for (int i = threadIdx.x; i < nbins; i += 256)
        if (c[i]) atomicAdd(&binCount[i], c[i]);
}

// ---- exclusive scan over bins (<=1024), init binCursor = binOff ----
__global__ void bin_scan(const int* __restrict__ binCount, int* __restrict__ binOff,
                         int* __restrict__ binCursor, int nb, int E) {
    __shared__ int s[256];
    int t = threadIdx.x, base = t * 4;
    int v0 = 0, v1 = 0, v2 = 0, v3 = 0;
    if (base + 0 < nb) v0 = binCount[base + 0];
    if (base + 1 < nb) v1 = binCount[base + 1];
    if (base + 2 < nb) v2 = binCount[base + 2];
    if (base + 3 < nb) v3 = binCount[base + 3];
    int sum = v0 + v1 + v2 + v3;
    s[t] = sum; __syncthreads();
    for (int off = 1; off < 256; off <<= 1) {
        int x = (t >= off) ? s[t - off] : 0;
        __syncthreads(); s[t] += x; __syncthreads();
    }
    int run = s[t] - sum;
    if (base + 0 < nb) { binOff[base + 0] = run; binCursor[base + 0] = run; } run += v0;
    if (base + 1 < nb) { binOff[base + 1] = run; binCursor[base + 1] = run; } run += v1;
    if (base + 2 < nb) { binOff[base + 2] = run; binCursor[base + 2] = run; } run += v2;
    if (base + 3 < nb) { binOff[base + 3] = run; binCursor[base + 3] = run; } run += v3;
    if (t == 0) binOff[nb] = E;
}

// ---- bin scatter: per-tile LDS count -> segment reservation -> append ----
__global__ void bin_scatter(const int* __restrict__ src, const int* __restrict__ dst,
                            int* __restrict__ binCursor, unsigned* __restrict__ packed,
                            int E, int nbins) {
    __shared__ int cnt[1024];
    __shared__ int cur[1024];
    int t = threadIdx.x;
    int s0 = blockIdx.x * SC_TILE, s1 = min(E, s0 + SC_TILE);
    for (int i = t; i < nbins; i += 256) cnt[i] = 0;
    __syncthreads();
    for (int e = s0 + t; e < s1; e += 256)
        atomicAdd(&cnt[dst[e] >> BIN_SHIFT], 1);
    __syncthreads();
    for (int b = t; b < nbins; b += 256)
        cur[b] = cnt[b] ? atomicAdd(&binCursor[b], cnt[b]) : 0;
    __syncthreads();
    for (int e = s0 + t; e < s1; e += 256) {       // tile re-read is L2-hot
        int d = dst[e];
        int b = d >> BIN_SHIFT;
        int pos = atomicAdd(&cur[b], 1);
        packed[pos] = ((unsigned)src[e] << BIN_SHIFT) | (unsigned)(d & (BIN_SIZE - 1));
    }
}

// ---- per-bin degree count: coalesced deg writes ----
__global__ void csr_count(const unsigned* __restrict__ packed, const int* __restrict__ binOff,
                          int* __restrict__ deg, int N) {
    __shared__ int c[BIN_SIZE];
    int t = threadIdx.x, b = blockIdx.x;
    for (int i = t; i < BIN_SIZE; i += 256) c[i] = 0;
    int j0 = binOff[b], j1 = binOff[b + 1];
    __syncthreads();
    for (int j = j0 + t; j < j1; j += 256)
        atomicAdd(&c[packed[j] & (BIN_SIZE - 1)], 1);
    __syncthreads();
    int base = b << BIN_SHIFT;
    for (int i = t; i < BIN_SIZE; i += 256) {
        int nd = base + i;
        if (nd < N) deg[nd] = c[i];
    }
}

// ---- per-bin CSR scatter: dests confined to bin's ~32KB esrc slice ----
__global__ void csr_scatter(const unsigned* __restrict__ packed, const int* __restrict__ binOff,
                            const int* __restrict__ rp, int* __restrict__ esrc, int N) {
    __shared__ int cur[BIN_SIZE];
    __shared__ int rps[BIN_SIZE];
    int t = threadIdx.x, b = blockIdx.x;
    int base = b << BIN_SHIFT;
    for (int i = t; i < BIN_SIZE; i += 256) {
        cur[i] = 0;
        int nd = base + i;
        rps[i] = (nd < N) ? rp[nd] : 0;
    }
    int j0 = binOff[b], j1 = binOff[b + 1];
    __syncthreads();
    for (int j = j0 + t; j < j1; j += 256) {
        unsigned p = packed[j];
        int dl = p & (BIN_SIZE - 1);
        int pos = rps[dl] + atomicAdd(&cur[dl], 1);
        esrc[pos] = (int)(p >> BIN_SHIFT);
    }
}

// ---- scan stage 1: per-block (1024 elems) exclusive scan + block sums ----
__global__ void scan1(const int* __restrict__ in, int* __restrict__ out,
                      int* __restrict__ bsum, int n) {
    __shared__ int s[256];
    int t = threadIdx.x, base = blockIdx.x * 1024 + t * 4;
    int v0 = 0, v1 = 0, v2 = 0, v3 = 0;
    if (base + 0 < n) v0 = in[base + 0];
    if (base + 1 < n) v1 = in[base + 1];
    if (base + 2 < n) v2 = in[base + 2];
    if (base + 3 < n) v3 = in[base + 3];
    int sum = v0 + v1 + v2 + v3;
    s[t] = sum; __syncthreads();
    for (int off = 1; off < 256; off <<= 1) {
        int x = (t >= off) ? s[t - off] : 0;
        __syncthreads(); s[t] += x; __syncthreads();
    }
    if (t == 255) bsum[blockIdx.x] = s[255];
    int run = s[t] - sum;
    if (base + 0 < n) out[base + 0] = run; run += v0;
    if (base + 1 < n) out[base + 1] = run; run += v1;
    if (base + 2 < n) out[base + 2] = run; run += v2;
    if (base + 3 < n) out[base + 3] = run;
}

__global__ void scan2(int* __restrict__ bsum, int nb) {
    __shared__ int s[256];
    int t = threadIdx.x, base = t * 4;
    int v0 = 0, v1 = 0, v2 = 0, v3 = 0;
    if (base + 0 < nb) v0 = bsum[base + 0];
    if (base + 1 < nb) v1 = bsum[base + 1];
    if (base + 2 < nb) v2 = bsum[base + 2];
    if (base + 3 < nb) v3 = bsum[base + 3];
    int sum = v0 + v1 + v2 + v3;
    s[t] = sum; __syncthreads();
    for (int off = 1; off < 256; off <<= 1) {
        int x = (t >= off) ? s[t - off] : 0;
        __syncthreads(); s[t] += x; __syncthreads();
    }
    int run = s[t] - sum;
    if (base + 0 < nb) bsum[base + 0] = run; run += v0;
    if (base + 1 < nb) bsum[base + 1] = run; run += v1;
    if (base + 2 < nb) bsum[base + 2] = run; run += v2;
    if (base + 3 < nb) bsum[base + 3] = run;
}

__global__ void scan3(int* __restrict__ out, const int* __restrict__ bsum,
                      int n, int N, int E) {
    int i = blockIdx.x * 256 + threadIdx.x;
    if (i < n) out[i] += bsum[i >> 10];
    if (i == 0) out[N] = E;
}

// ---- CSR aggregation: software-pipelined over nodes ----
// lane group g=lane&7 owns cols 8g..8g+7; sub=lane>>3 picks the edge.
// rp[dn] prefetched a full node ahead; next esrc chunk prefetched under
// fold/write. All shuffles at full exec (wave-uniform sections).
__global__ void agg_csr(const __half* __restrict__ tmp, const int* __restrict__ rp,
                        const int* __restrict__ esrc, const float* __restrict__ dinv,
                        const float* __restrict__ bias, float* __restrict__ outf,
                        __half* __restrict__ houtp, int N, int do_relu) {
    const int wave = threadIdx.x >> 6;
    const int lane = threadIdx.x & 63;
    const int g    = lane & 7;       // col group
    const int sub  = lane >> 3;      // edge slot 0..7
    const int stride = gridDim.x * 4;

    int d = blockIdx.x * 4 + wave;
    if (d >= N) return;
    int j0 = rp[d], j1 = rp[d + 1];
    int sp = (j0 + lane < j1) ? esrc[j0 + lane] : 0;   // first chunk prefetch

    while (d < N) {
        const int dn = d + stride;
        int nj0 = 0, nj1 = 0;
        if (dn < N) { nj0 = rp[dn]; nj1 = rp[dn + 1]; }   // in flight during gathers

        // self-loop term (branchless: lanes sub!=0 contribute 0)
        uint4 vself = make_uint4(0, 0, 0, 0);
        if (sub == 0) vself = ((const uint4*)(tmp + (size_t)d * HID))[g];
        float acc[8];
        {
            const __half2* h2 = (const __half2*)&vself;
            #pragma unroll
            for (int i = 0; i < 4; ++i) {
                float2 f = __half22float2(h2[i]);
                acc[2 * i]     = f.x;
                acc[2 * i + 1] = f.y;
            }
        }

        int cs = sp, base = j0;
        while (base < j1) {
            int cnt = min(64, j1 - base);
            int jj = 0;
            for (; jj + 16 <= cnt; jj += 16) {       // 2-deep, unguarded
                int s0 = __shfl(cs, jj + sub);
                int s1 = __shfl(cs, jj + 8 + sub);
                uint4 v0 = ((const uint4*)(tmp + (size_t)s0 * HID))[g];
                uint4 v1 = ((const uint4*)(tmp + (size_t)s1 * HID))[g];
                const __half2* h0 = (const __half2*)&v0;
                const __half2* h1 = (const __half2*)&v1;
                #pragma unroll
                for (int i = 0; i < 4; ++i) {
                    float2 f0 = __half22float2(h0[i]);
                    float2 f1 = __half22float2(h1[i]);
                    acc[2 * i]     += f0.x + f1.x;
                    acc[2 * i + 1] += f0.y + f1.y;
                }
            }
            if (jj + 8 <= cnt) {                     // 1-deep, unguarded
                int s0 = __shfl(cs, jj + sub);
                uint4 v0 = ((const uint4*)(tmp + (size_t)s0 * HID))[g];
                const __half2* h0 = (const __half2*)&v0;
                #pragma unroll
                for (int i = 0; i < 4; ++i) {
                    float2 f = __half22float2(h0[i]);
                    acc[2 * i] += f.x; acc[2 * i + 1] += f.y;
                }
                jj += 8;
            }
            if (jj < cnt) {                          // clamped tail
                int e = jj + sub;
                int s0 = __shfl(cs, min(e, cnt - 1));   // full exec
                if (e < cnt) {
                    uint4 v = ((const uint4*)(tmp + (size_t)s0 * HID))[g];
                    const __half2* h2 = (const __half2*)&v;
                    #pragma unroll
                    for (int i = 0; i < 4; ++i) {
                        float2 f = __half22float2(h2[i]);
                        acc[2 * i] += f.x; acc[2 * i + 1] += f.y;
                    }
                }
            }
            base += 64;
            if (base < j1) {
                int rem = j1 - base;
                cs = (lane < rem) ? esrc[base + lane] : 0;
            }
        }

        // prefetch next node's first esrc chunk (nj0 arrived by now);
        // latency hides under fold + write + next self-loop.
        int nsp = 0;
        if (dn < N) nsp = (nj0 + lane < nj1) ? esrc[nj0 + lane] : 0;

        // fold the 8 sub replicas (butterfly over lane bits 3,4,5)
        #pragma unroll
        for (int i = 0; i < 8; ++i) {
            float a = acc[i];
            a += __shfl_xor(a, 8);
            a += __shfl_xor(a, 16);
            a += __shfl_xor(a, 32);
            acc[i] = a;
        }
        if (sub == 0) {        // lanes 0..7 hold the row
            float di = dinv[d];
            float o[8];
            #pragma unroll
            for (int i = 0; i < 8; ++i) o[i] = di * acc[i];
            if (bias != nullptr) {
                #pragma unroll
                for (int i = 0; i < 8; ++i) o[i] += bias[g * 8 + i];
            }
            if (do_relu) {
                #pragma unroll
                for (int i = 0; i < 8; ++i) o[i] = fmaxf(o[i], 0.0f);
            }
            if (houtp != nullptr) {              // fp16 row: 16B per lane
                __half2 ph[4];
                #pragma unroll
                for (int i = 0; i < 4; ++i)
                    ph[i] = __halves2half2(__float2half_rn(o[2 * i]),
                                           __float2half_rn(o[2 * i + 1]));
                *(uint4*)&houtp[(size_t)d * HID + g * 8] = *(uint4*)ph;
            } else {
                float* orow = &outf[(size_t)d * HID + g * 8];
                *(float4*)orow       = make_float4(o[0], o[1], o[2], o[3]);
                *(float4*)(orow + 4) = make_float4(o[4], o[5], o[6], o[7]);
            }
        }
        d = dn; j0 = nj0; j1 = nj1; sp = nsp;
    }
}

extern "C" void kernel_launch(void* const* d_in, const int* in_sizes, int n_in,
                              void* d_out, int out_size, void* d_ws, size_t ws_size,
                              hipStream_t stream) {
    const float* x     = (const float*)d_in[0];   // f32 [N,128]
    const int*   ei    = (const int*)d_in[1];     // int32 [2,E]
    const float* W_in  = (const float*)d_in[2];   // f32 [128,64]
    const float* b_in  = (const float*)d_in[3];   // f32 [64]
    const float* W_h   = (const float*)d_in[4];   // f32 [3,64,64]
    const float* b_h   = (const float*)d_in[5];   // f32 [3,64]
    const float* W_out = (const float*)d_in[6];   // f32 [64,64]

    const int K0 = in_sizes[2] / HID;   // 128
    const int N  = in_sizes[0] / K0;    // 100000
    const int E  = in_sizes[1] / 2;     // 1600000
    const int* srcp = ei;
    const int* dstp = ei + E;

    const int NH = N * HID;
    const size_t Npad = ((size_t)N + 255) & ~(size_t)255;
    const int nbins = (N + BIN_SIZE - 1) >> BIN_SHIFT;   // 196

    float*  ACC = (float*)d_out;                  // final output f32 [N,64]
    __half* h16 = (__half*)d_out;                 // intermediate H fp16 (same storage)

    // ws layout (~20.5MB, inside the proven region):
    float*    dinv   = (float*)d_ws;              // Npad f32          0.4 MB
    __half*   tmp    = (__half*)(dinv + Npad);    // NH half          12.8 MB
    unsigned* packed = (unsigned*)tmp;            // E u32 (ALIASES tmp: CSR build
                                                  //  finishes before first gemm)
    int*      degi   = (int*)(tmp + NH);          // Npad              0.4 MB
    int*      rp     = degi + Npad;               // Npad+256          0.4 MB
    int*      bsum   = rp + Npad + 256;           // 1024
    int*      esrc   = bsum + 1024;               // E                 6.4 MB
    int*      binCount  = esrc + E;               // 1024
    int*      binOff    = binCount + 1024;        // 1025
    int*      binCursor = binOff + 1026;          // 1024
    uintptr_t wf_addr = (uintptr_t)(binCursor + 1024);
    wf_addr = (wf_addr + 15) & ~(uintptr_t)15;
    __half*   wfrag  = (__half*)wf_addr;          // 3072 x 8 fp16    48 KB

    const int tgrid = (N + 127) / 128;
    const int agrid = 2048;                       // persistent waves
    const int nb    = (N + 1023) / 1024;
    const int sgrid = (E + SC_TILE - 1) / SC_TILE;

    // ---- W fragment prep + 2-level counting sort CSR build ----
    wfrag_prep<<<48, 64, 0, stream>>>(W_in, W_h, W_out, wfrag);
    zero_i<<<1, 256, 0, stream>>>(binCount, nbins);
    bin_count<<<nbins, 256, 0, stream>>>(dstp, binCount, E, nbins);
    bin_scan<<<1, 256, 0, stream>>>(binCount, binOff, binCursor, nbins, E);
    bin_scatter<<<sgrid, 256, 0, stream>>>(srcp, dstp, binCursor, packed, E, nbins);
    csr_count<<<nbins, 256, 0, stream>>>(packed, binOff, degi, N);
    dinv_k<<<(N + 255) / 256, 256, 0, stream>>>(degi, dinv, N);
    scan1<<<nb, 256, 0, stream>>>(degi, rp, bsum, N);
    scan2<<<1, 256, 0, stream>>>(bsum, nb);
    scan3<<<(N + 255) / 256, 256, 0, stream>>>(rp, bsum, N, N, E);
    csr_scatter<<<nbins, 256, 0, stream>>>(packed, binOff, rp, esrc, N);

    // ---- 5 GCN convs (MFMA GEMMs; fp16 inter-layer H) ----
    gemm_mfma<true, 4><<<tgrid, 256, 0, stream>>>(x, wfrag, dinv, tmp, N);
    agg_csr<<<agrid, 256, 0, stream>>>(tmp, rp, esrc, dinv, b_in, nullptr, h16, N, 0);
    for (int l = 0; l < 3; ++l) {
        gemm_mfma<false, 2><<<tgrid, 256, 0, stream>>>(
            h16, wfrag + (size_t)(1024 + l * 512) * 8, dinv, tmp, N);
        agg_csr<<<agrid, 256, 0, stream>>>(tmp, rp, esrc, dinv, b_h + (size_t)l * HID,
                                           nullptr, h16, N, 1);
    }
    gemm_mfma<false, 2><<<tgrid, 256, 0, stream>>>(
        h16, wfrag + (size_t)2560 * 8, dinv, tmp, N);
    agg_csr<<<agrid, 256, 0, stream>>>(tmp, rp, esrc, dinv, nullptr, ACC, nullptr, N, 0);
}